// Round 10
// baseline (353.317 us; speedup 1.0000x reference)
//
#include <hip/hip_runtime.h>

#define NB 32768
#define DD 16
#define HH 64
#define EPB 16

typedef __attribute__((ext_vector_type(8))) short short8;
typedef __attribute__((ext_vector_type(2))) float f32x2;
typedef __attribute__((ext_vector_type(4))) float f32x4;
typedef __attribute__((ext_vector_type(4))) unsigned uint4v;

union Frag { short8 s; uint4v u; unsigned d[4]; };

struct Params {
  const float *ts, *x0;
  const float *W0,*b0,*g0,*gb0,*hb0;
  const float *W1,*b1,*g1,*gb1,*hb1;
  const float *W2,*b2,*g2,*gb2,*hb2;
  const float *W3,*b3,*g3,*gb3,*hb3;
  float *out;
};

__device__ __forceinline__ float bfs(unsigned short u){
  return __uint_as_float(((unsigned)u)<<16);
}
__device__ __forceinline__ unsigned short f2bf(float f){   // full RNE (init only)
  unsigned u=__float_as_uint(f);
  return (unsigned short)((u + 0x7FFFu + ((u>>16)&1u))>>16);
}
__device__ __forceinline__ unsigned pk2bf(float lo, float hi){
  unsigned a=__float_as_uint(lo)+0x8000u;
  unsigned b=__float_as_uint(hi)+0x8000u;
  return __builtin_amdgcn_perm(b, a, 0x07060302u);
}
__device__ __forceinline__ unsigned short f2bf1(float f){
  return (unsigned short)((__float_as_uint(f)+0x8000u)>>16);
}
__device__ __forceinline__ float sigm(float u){
  return __builtin_amdgcn_rcpf(1.0f+__builtin_amdgcn_exp2f(-1.44269504f*u));
}
#define WV() __builtin_amdgcn_wave_barrier()
#define MFMA(A,B,C) __builtin_amdgcn_mfma_f32_16x16x32_bf16((A),(B),(C),0,0,0)

// gated-tanh epilogue; sc = {g, gb, hb, b}; h -> bf16, s -> bf16
__device__ __forceinline__ void fwd_epi(const f32x4& c, float tcur,
    const float4 sc,
    unsigned short* __restrict__ hdst, unsigned short* __restrict__ sdst,
    int jw, int q)
{
  const float gate = sigm(tcur*sc.x+sc.y);
  const float gk   = gate*2.88539008f;
  const float tbk  = (tcur*sc.z)*2.88539008f;
  const float g4   = 4.0f*gate;
  const f32x2 c01={c[0],c[1]}, c23={c[2],c[3]};
  const f32x2 pre01 = c01*gk + tbk;
  const f32x2 pre23 = c23*gk + tbk;
  const f32x2 e01={__builtin_amdgcn_exp2f(pre01[0]),__builtin_amdgcn_exp2f(pre01[1])};
  const f32x2 e23={__builtin_amdgcn_exp2f(pre23[0]),__builtin_amdgcn_exp2f(pre23[1])};
  const f32x2 d01=e01+1.0f, d23=e23+1.0f;
  const f32x2 rc01={__builtin_amdgcn_rcpf(d01[0]),__builtin_amdgcn_rcpf(d01[1])};
  const f32x2 rc23={__builtin_amdgcn_rcpf(d23[0]),__builtin_amdgcn_rcpf(d23[1])};
  const f32x2 th01 = rc01*-2.0f + 1.0f;
  const f32x2 th23 = rc23*-2.0f + 1.0f;
  const f32x2 om01 = 1.0f - rc01, om23 = 1.0f - rc23;
  const f32x2 sv01 = (rc01*g4)*om01, sv23 = (rc23*g4)*om23;
  const int el0=q*4;
  hdst[(el0+0)*72+jw]=f2bf1(th01[0]);
  hdst[(el0+1)*72+jw]=f2bf1(th01[1]);
  hdst[(el0+2)*72+jw]=f2bf1(th23[0]);
  hdst[(el0+3)*72+jw]=f2bf1(th23[1]);
  sdst[(el0+0)*72+jw]=f2bf1(sv01[0]);
  sdst[(el0+1)*72+jw]=f2bf1(sv01[1]);
  sdst[(el0+2)*72+jw]=f2bf1(sv23[0]);
  sdst[(el0+3)*72+jw]=f2bf1(sv23[1]);
}

// layer-0 variant: s written as f32 at stride 76 (padded, conflict-free)
__device__ __forceinline__ void fwd_epi0(const f32x4& c, float tcur,
    const float4 sc,
    unsigned short* __restrict__ hdst, float* __restrict__ sdstf,
    int jw, int q)
{
  const float gate = sigm(tcur*sc.x+sc.y);
  const float gk   = gate*2.88539008f;
  const float tbk  = (tcur*sc.z)*2.88539008f;
  const float g4   = 4.0f*gate;
  const f32x2 c01={c[0],c[1]}, c23={c[2],c[3]};
  const f32x2 pre01 = c01*gk + tbk;
  const f32x2 pre23 = c23*gk + tbk;
  const f32x2 e01={__builtin_amdgcn_exp2f(pre01[0]),__builtin_amdgcn_exp2f(pre01[1])};
  const f32x2 e23={__builtin_amdgcn_exp2f(pre23[0]),__builtin_amdgcn_exp2f(pre23[1])};
  const f32x2 d01=e01+1.0f, d23=e23+1.0f;
  const f32x2 rc01={__builtin_amdgcn_rcpf(d01[0]),__builtin_amdgcn_rcpf(d01[1])};
  const f32x2 rc23={__builtin_amdgcn_rcpf(d23[0]),__builtin_amdgcn_rcpf(d23[1])};
  const f32x2 th01 = rc01*-2.0f + 1.0f;
  const f32x2 th23 = rc23*-2.0f + 1.0f;
  const f32x2 om01 = 1.0f - rc01, om23 = 1.0f - rc23;
  const f32x2 sv01 = (rc01*g4)*om01, sv23 = (rc23*g4)*om23;
  const int el0=q*4;
  hdst[(el0+0)*72+jw]=f2bf1(th01[0]);
  hdst[(el0+1)*72+jw]=f2bf1(th01[1]);
  hdst[(el0+2)*72+jw]=f2bf1(th23[0]);
  hdst[(el0+3)*72+jw]=f2bf1(th23[1]);
  sdstf[(el0+0)*76+jw]=sv01[0];
  sdstf[(el0+1)*76+jw]=sv01[1];
  sdstf[(el0+2)*76+jw]=sv23[0];
  sdstf[(el0+3)*76+jw]=sv23[1];
}

// R10: launch-bounds cap experiment. Re-fit of all 10 rounds: the 2nd
// __launch_bounds__ arg acts as a waves-per-EU CAP on this toolchain
// ((256,3)->3 blocks everywhere regardless of LDS; (256,2)->2 blocks in R9;
// (512,2)->1 block in R3/R4; allocator targets 2x the arg: 64/84/128 VGPR).
// Fix: NO waves-per-eu clause. Backend sizes VGPRs from LDS-implied
// occupancy: LDS ~34.3K -> 4 blocks -> VGPR budget 128 = exactly R9's
// allocation. Body = R9 (reg B-frags w2r/b3r, hvt union, B5) + w3tt->bf16
// (-2.5KB, margin vs any truly-reserved LDS; 4x137K well under 160K).
__global__ __launch_bounds__(256) void traj_kernel(Params p){
  __shared__ __align__(16) float w0f[DD][76];              // W0[a][i] f32, padded
  __shared__ __align__(16) unsigned short w3b[HH][20];     // W3[j][a] bf16 (trace)
  __shared__ __align__(16) unsigned short w0t[HH][16];     // W0^T[jw][k<16] bf16 (L0 B-frag)
  __shared__ __align__(16) float4 lscA[3][64];             // {g,gb,hb,b} per col, layers 0-2
  __shared__ __align__(16) float4 lsc3[16];                // layer 3 (by m)
  __shared__ __align__(16) unsigned short xh[DD][16];      // x hi-bf16 (K>=16 via zero frag)
  __shared__ __align__(16) unsigned short xl[DD][16];      // x lo-bf16
  // UNION: planes 0/1 = fwd activations h0/h1 (live L0..L3); plane wv = vt
  // (live only in el-loop, after B5). h2 reuses plane 0.
  __shared__ __align__(16) unsigned short hvt[4][DD][72];
  __shared__ __align__(16) float sb0f[EPB][76];            // s0 f32, padded
  __shared__ __align__(16) unsigned short sb12[2][EPB][72];// s1,s2 bf16
  __shared__ __align__(16) float sig3w[4][DD];
  __shared__ __align__(16) float dxs[4][4][17];            // per-wave dx slice [wv][r][m]

  const int tid = threadIdx.x;
  const int e   = tid>>4;
  const int a   = tid&15;
  const int wv  = tid>>6;
  const int lane= tid&63;
  const int m   = lane&15;
  const int q   = lane>>4;
  const int b   = blockIdx.x*EPB + e;
  const int jw  = wv*16 + m;     // forward output column of this lane

  // ---- persistent register weight fragments ----
  short8 f1fr[2], f2fr[2];
  short8 b1fr[2][4];              // tangent GEMM1 B-frags, N-permuted: cols 4m+nt
  short8 w2r[2][4];               // tangent GEMM2 B-frags
  short8 b3r[2];                  // L3 B-frags
  {
    #pragma unroll
    for(int kk=0;kk<2;++kk){
      #pragma unroll
      for(int j=0;j<8;++j){
        const int k=kk*32+q*8+j;
        f1fr[kk][j]=(short)f2bf(p.W1[k*HH+jw]);
        f2fr[kk][j]=(short)f2bf(p.W2[k*HH+jw]);
        b3r[kk][j]=(short)f2bf(p.W3[k*DD+m]);
      }
      #pragma unroll
      for(int nt=0;nt<4;++nt){
        #pragma unroll
        for(int j=0;j<8;++j){
          const int k=kk*32+q*8+j;
          b1fr[kk][nt][j]=(short)f2bf(p.W1[k*HH+4*m+nt]);
          w2r[kk][nt][j]=(short)f2bf(p.W2[k*HH+4*m+nt]);
        }
      }
    }
  }

  // ---- one-time LDS staging ----
  for(int idx=tid; idx<DD*HH; idx+=256) w0f[idx>>6][idx&63]=p.W0[idx];    // f32
  for(int idx=tid; idx<HH*DD; idx+=256) w3b[idx>>4][idx&15]=f2bf(p.W3[idx]); // bf16
  for(int idx=tid; idx<HH*16; idx+=256){
    const int c_=idx>>4, k=idx&15;
    w0t[c_][k]=f2bf(p.W0[k*HH+c_]);
  }
  if(tid<64)            lscA[0][tid]    =make_float4(p.g0[tid],p.gb0[tid],p.hb0[tid],p.b0[tid]);
  else if(tid<128)      lscA[1][tid-64] =make_float4(p.g1[tid-64],p.gb1[tid-64],p.hb1[tid-64],p.b1[tid-64]);
  else if(tid<192)      lscA[2][tid-128]=make_float4(p.g2[tid-128],p.gb2[tid-128],p.hb2[tid-128],p.b2[tid-128]);
  else if(tid<208)      lsc3[tid-192]   =make_float4(p.g3[tid-192],p.gb3[tid-192],p.hb3[tid-192],p.b3[tid-192]);
  __syncthreads();

  float zbx = p.x0[b*DD+a];
  p.out[b*DD+a]=zbx;
  float trp[4]={0.f,0.f,0.f,0.f};
  float dvp=0.f;

  #pragma unroll 1
  for(int step=0; step<2; ++step){
    const float t0=p.ts[step], t1=p.ts[step+1];
    const float hs=t1-t0;
    float dzx=0.f;
    float zwx=zbx;
    #pragma unroll 1
    for(int stage=0; stage<4; ++stage){
      const float cin=(stage==0)?0.f:((stage==3)?1.f:0.5f);
      const float tcur=t0+cin*hs;
      const float wg=(stage==0||stage==3)?1.f:2.f;
      const float fs=hs*(1.f/6.f)*wg;
      const float fs5=0.5f*fs;

      // producer writes x as pre-split hi/lo bf16
      {
        const unsigned ux=__float_as_uint(zwx);
        xh[e][a]=(unsigned short)(ux>>16);
        xl[e][a]=f2bf1(zwx-__uint_as_float(ux&0xFFFF0000u));
      }
      __syncthreads();                       // B1 (also: all prior vt reads done)

      // ---------- L0: X @ W0 (hi/lo; K>=16 rows zero via zero frags) ----------
      float4 sc0=lscA[0][jw];
      f32x4 c={sc0.w,sc0.w,sc0.w,sc0.w};
      {
        short8 f0fr=short8{0,0,0,0,0,0,0,0};
        short8 ah=f0fr, al=f0fr;
        if(q<2){
          f0fr=*reinterpret_cast<const short8*>(&w0t[jw][q*8]);
          ah  =*reinterpret_cast<const short8*>(&xh[m][q*8]);
          al  =*reinterpret_cast<const short8*>(&xl[m][q*8]);
        }
        c=MFMA(ah,f0fr,c); c=MFMA(al,f0fr,c);
      }
      fwd_epi0(c,tcur,sc0,&hvt[0][0][0],&sb0f[0][0],jw,q);
      __syncthreads();                       // B2

      // ---------- L1 ----------
      float4 sc1=lscA[1][jw];
      c=f32x4{sc1.w,sc1.w,sc1.w,sc1.w};
      #pragma unroll
      for(int kk=0;kk<2;++kk){
        const short8 ah=*reinterpret_cast<const short8*>(&hvt[0][m][kk*32+q*8]);
        c=MFMA(ah,f1fr[kk],c);
      }
      fwd_epi(c,tcur,sc1,&hvt[1][0][0],&sb12[0][0][0],jw,q);
      __syncthreads();                       // B3

      // ---------- L2 ----------
      float4 sc2=lscA[2][jw];
      c=f32x4{sc2.w,sc2.w,sc2.w,sc2.w};
      #pragma unroll
      for(int kk=0;kk<2;++kk){
        const short8 ah=*reinterpret_cast<const short8*>(&hvt[1][m][kk*32+q*8]);
        c=MFMA(ah,f2fr[kk],c);
      }
      fwd_epi(c,tcur,sc2,&hvt[0][0][0],&sb12[1][0][0],jw,q);  // h2 -> plane 0
      __syncthreads();                       // B4

      // ---------- L3: dx ----------
      float4 sc3=lsc3[m];
      c=f32x4{sc3.w,sc3.w,sc3.w,sc3.w};
      #pragma unroll
      for(int kk=0;kk<2;++kk){
        const short8 ah=*reinterpret_cast<const short8*>(&hvt[0][m][kk*32+q*8]);
        c=MFMA(ah,b3r[kk],c);
      }
      const float gate3=sigm(tcur*sc3.x+sc3.y);
      const float tb3=tcur*sc3.z;
      if(q==wv){
        #pragma unroll
        for(int r=0;r<4;++r)
          dxs[wv][r][m]=c[r]*gate3+tb3;
      }
      if(q==0) sig3w[wv][m]=gate3;
      WV();
      const float dxk=dxs[wv][q][m];         // = dx[e][a]
      dvp += fs5*dxk*dxk;

      // ---------- trace factors (once per stage, pk; W3 from bf16) ----------
      f32x2 tf2[4][2];
      {
        const f32x4 sg4=*reinterpret_cast<const f32x4*>(&sig3w[wv][q*4]);
        const f32x2 sgA={sg4[0],sg4[1]}, sgB={sg4[2],sg4[3]};
        #pragma unroll
        for(int nt=0;nt<4;++nt){
          const unsigned* wp=reinterpret_cast<const unsigned*>(&w3b[4*m+nt][q*4]);
          const unsigned lo=wp[0], hi=wp[1];
          tf2[nt][0]=sgA*f32x2{__uint_as_float(lo<<16), __uint_as_float(lo&0xFFFF0000u)};
          tf2[nt][1]=sgB*f32x2{__uint_as_float(hi<<16), __uint_as_float(hi&0xFFFF0000u)};
        }
      }

      __syncthreads();                       // B5: all L3 hvt[0] reads done
                                             //     before el-loop vt writes

      // ---------- tangent per element (nt-paired accumulators) ----------
      #pragma unroll
      for(int el=0; el<4; ++el){
        const int ee=wv*4+el;
        // A0 = W0 (f32) ⊙ s0 (f32) -> bf16 pack; no unpacking
        Frag a0[2];
        #pragma unroll
        for(int kk=0;kk<2;++kk){
          const f32x4 wa=*reinterpret_cast<const f32x4*>(&w0f[m][kk*32+q*8]);
          const f32x4 wb=*reinterpret_cast<const f32x4*>(&w0f[m][kk*32+q*8+4]);
          const f32x4 sa=*reinterpret_cast<const f32x4*>(&sb0f[ee][kk*32+q*8]);
          const f32x4 sc_=*reinterpret_cast<const f32x4*>(&sb0f[ee][kk*32+q*8+4]);
          a0[kk].d[0]=pk2bf(wa[0]*sa[0], wa[1]*sa[1]);
          a0[kk].d[1]=pk2bf(wa[2]*sa[2], wa[3]*sa[3]);
          a0[kk].d[2]=pk2bf(wb[0]*sc_[0], wb[1]*sc_[1]);
          a0[kk].d[3]=pk2bf(wb[2]*sc_[2], wb[3]*sc_[3]);
        }
        // GEMM1 in nt pairs: only 2 acc quads live
        #pragma unroll
        for(int np=0; np<2; ++np){
          f32x4 cA={0,0,0,0}, cB={0,0,0,0};
          #pragma unroll
          for(int kk=0;kk<2;++kk){
            cA=MFMA(a0[kk].s,b1fr[kk][2*np  ],cA);
            cB=MFMA(a0[kk].s,b1fr[kk][2*np+1],cB);
          }
          const unsigned s1d=*reinterpret_cast<const unsigned*>(&sb12[0][ee][4*m+2*np]);
          const float sA_=__uint_as_float(s1d<<16), sB_=__uint_as_float(s1d&0xFFFF0000u);
          const f32x4 prA=cA*sA_, prB=cB*sB_;
          #pragma unroll
          for(int r=0;r<4;++r)
            *reinterpret_cast<unsigned*>(&hvt[wv][q*4+r][4*m+2*np])=pk2bf(prA[r],prB[r]);
        }
        WV();
        short8 a2[2];
        #pragma unroll
        for(int kk=0;kk<2;++kk)
          a2[kk]=*reinterpret_cast<const short8*>(&hvt[wv][m][kk*32+q*8]);
        // GEMM2 in nt pairs, B-frags from persistent registers (w2r)
        float tr=0.f;
        #pragma unroll
        for(int np=0; np<2; ++np){
          f32x4 cA={0,0,0,0}, cB={0,0,0,0};
          #pragma unroll
          for(int kk=0;kk<2;++kk){
            cA=MFMA(a2[kk],w2r[kk][2*np  ],cA);
            cB=MFMA(a2[kk],w2r[kk][2*np+1],cB);
          }
          const unsigned s2d=*reinterpret_cast<const unsigned*>(&sb12[1][ee][4*m+2*np]);
          const float s20=__uint_as_float(s2d<<16), s21=__uint_as_float(s2d&0xFFFF0000u);
          const f32x2 tA = f32x2{cA[0],cA[1]}*tf2[2*np  ][0] + f32x2{cA[2],cA[3]}*tf2[2*np  ][1];
          const f32x2 tB = f32x2{cB[0],cB[1]}*tf2[2*np+1][0] + f32x2{cB[2],cB[3]}*tf2[2*np+1][1];
          tr += (tA[0]+tA[1])*s20 + (tB[0]+tB[1])*s21;
        }
        trp[el] += fs*tr;
        WV();
      }

      // ---------- RK4 state update ----------
      dzx += fs*dxk;
      const float cn=(stage==2)?1.f:0.5f;
      if(stage<3) zwx=zbx+cn*hs*dxk;
    }
    zbx += dzx;
    p.out[(step+1)*(NB*DD)+b*DD+a]=zbx;
  }

  // ---------- deferred reductions ----------
  #pragma unroll
  for(int el=0; el<4; ++el){
    float v=trp[el];
    #pragma unroll
    for(int mk=32;mk>=1;mk>>=1) v+=__shfl_xor(v,mk,64);
    if(lane==el) p.out[3*NB*DD + blockIdx.x*EPB + wv*4 + el]=v;
  }
  {
    float v=dvp;
    #pragma unroll
    for(int mk=8;mk>=1;mk>>=1) v+=__shfl_xor(v,mk,16);
    if(a==0){
      p.out[3*NB*DD+NB+b]=fabsf(v);
      p.out[3*NB*DD+2*NB+b]=0.f;
    }
  }
}

extern "C" void kernel_launch(void* const* d_in, const int* in_sizes, int n_in,
                              void* d_out, int out_size, void* d_ws, size_t ws_size,
                              hipStream_t stream){
  Params p;
  p.ts  = (const float*)d_in[0];
  p.x0  = (const float*)d_in[1];
  p.W0  = (const float*)d_in[2];  p.b0 =(const float*)d_in[3];
  p.g0  = (const float*)d_in[4];  p.gb0=(const float*)d_in[5];  p.hb0=(const float*)d_in[6];
  p.W1  = (const float*)d_in[7];  p.b1 =(const float*)d_in[8];
  p.g1  = (const float*)d_in[9];  p.gb1=(const float*)d_in[10]; p.hb1=(const float*)d_in[11];
  p.W2  = (const float*)d_in[12]; p.b2 =(const float*)d_in[13];
  p.g2  = (const float*)d_in[14]; p.gb2=(const float*)d_in[15]; p.hb2=(const float*)d_in[16];
  p.W3  = (const float*)d_in[17]; p.b3 =(const float*)d_in[18];
  p.g3  = (const float*)d_in[19]; p.gb3=(const float*)d_in[20]; p.hb3=(const float*)d_in[21];
  p.out = (float*)d_out;
  hipLaunchKernelGGL(traj_kernel, dim3(NB/EPB), dim3(256), 0, stream, p);
}

// Round 11
// 245.886 us; speedup vs baseline: 1.4369x; 1.4369x over previous
//
#include <hip/hip_runtime.h>

#define NB 32768
#define DD 16
#define HH 64
#define EPB 16

typedef __attribute__((ext_vector_type(8))) short short8;
typedef __attribute__((ext_vector_type(2))) float f32x2;
typedef __attribute__((ext_vector_type(4))) float f32x4;
typedef __attribute__((ext_vector_type(4))) unsigned uint4v;

union Frag { short8 s; uint4v u; unsigned d[4]; };

struct Params {
  const float *ts, *x0;
  const float *W0,*b0,*g0,*gb0,*hb0;
  const float *W1,*b1,*g1,*gb1,*hb1;
  const float *W2,*b2,*g2,*gb2,*hb2;
  const float *W3,*b3,*g3,*gb3,*hb3;
  float *out;
};

__device__ __forceinline__ float bfs(unsigned short u){
  return __uint_as_float(((unsigned)u)<<16);
}
__device__ __forceinline__ unsigned short f2bf(float f){   // full RNE (init only)
  unsigned u=__float_as_uint(f);
  return (unsigned short)((u + 0x7FFFu + ((u>>16)&1u))>>16);
}
__device__ __forceinline__ unsigned pk2bf(float lo, float hi){
  unsigned a=__float_as_uint(lo)+0x8000u;
  unsigned b=__float_as_uint(hi)+0x8000u;
  return __builtin_amdgcn_perm(b, a, 0x07060302u);
}
__device__ __forceinline__ unsigned short f2bf1(float f){
  return (unsigned short)((__float_as_uint(f)+0x8000u)>>16);
}
__device__ __forceinline__ float sigm(float u){
  return __builtin_amdgcn_rcpf(1.0f+__builtin_amdgcn_exp2f(-1.44269504f*u));
}
#define WV() __builtin_amdgcn_wave_barrier()
#define MFMA(A,B,C) __builtin_amdgcn_mfma_f32_16x16x32_bf16((A),(B),(C),0,0,0)

// gated-tanh epilogue; sc = {g, gb, hb, b}; h -> bf16, s -> bf16
__device__ __forceinline__ void fwd_epi(const f32x4& c, float tcur,
    const float4 sc,
    unsigned short* __restrict__ hdst, unsigned short* __restrict__ sdst,
    int jw, int q)
{
  const float gate = sigm(tcur*sc.x+sc.y);
  const float gk   = gate*2.88539008f;
  const float tbk  = (tcur*sc.z)*2.88539008f;
  const float g4   = 4.0f*gate;
  const f32x2 c01={c[0],c[1]}, c23={c[2],c[3]};
  const f32x2 pre01 = c01*gk + tbk;
  const f32x2 pre23 = c23*gk + tbk;
  const f32x2 e01={__builtin_amdgcn_exp2f(pre01[0]),__builtin_amdgcn_exp2f(pre01[1])};
  const f32x2 e23={__builtin_amdgcn_exp2f(pre23[0]),__builtin_amdgcn_exp2f(pre23[1])};
  const f32x2 d01=e01+1.0f, d23=e23+1.0f;
  const f32x2 rc01={__builtin_amdgcn_rcpf(d01[0]),__builtin_amdgcn_rcpf(d01[1])};
  const f32x2 rc23={__builtin_amdgcn_rcpf(d23[0]),__builtin_amdgcn_rcpf(d23[1])};
  const f32x2 th01 = rc01*-2.0f + 1.0f;
  const f32x2 th23 = rc23*-2.0f + 1.0f;
  const f32x2 om01 = 1.0f - rc01, om23 = 1.0f - rc23;
  const f32x2 sv01 = (rc01*g4)*om01, sv23 = (rc23*g4)*om23;
  const int el0=q*4;
  hdst[(el0+0)*72+jw]=f2bf1(th01[0]);
  hdst[(el0+1)*72+jw]=f2bf1(th01[1]);
  hdst[(el0+2)*72+jw]=f2bf1(th23[0]);
  hdst[(el0+3)*72+jw]=f2bf1(th23[1]);
  sdst[(el0+0)*72+jw]=f2bf1(sv01[0]);
  sdst[(el0+1)*72+jw]=f2bf1(sv01[1]);
  sdst[(el0+2)*72+jw]=f2bf1(sv23[0]);
  sdst[(el0+3)*72+jw]=f2bf1(sv23[1]);
}

// layer-0 variant: s written as f32 at stride 76 (padded, conflict-free)
__device__ __forceinline__ void fwd_epi0(const f32x4& c, float tcur,
    const float4 sc,
    unsigned short* __restrict__ hdst, float* __restrict__ sdstf,
    int jw, int q)
{
  const float gate = sigm(tcur*sc.x+sc.y);
  const float gk   = gate*2.88539008f;
  const float tbk  = (tcur*sc.z)*2.88539008f;
  const float g4   = 4.0f*gate;
  const f32x2 c01={c[0],c[1]}, c23={c[2],c[3]};
  const f32x2 pre01 = c01*gk + tbk;
  const f32x2 pre23 = c23*gk + tbk;
  const f32x2 e01={__builtin_amdgcn_exp2f(pre01[0]),__builtin_amdgcn_exp2f(pre01[1])};
  const f32x2 e23={__builtin_amdgcn_exp2f(pre23[0]),__builtin_amdgcn_exp2f(pre23[1])};
  const f32x2 d01=e01+1.0f, d23=e23+1.0f;
  const f32x2 rc01={__builtin_amdgcn_rcpf(d01[0]),__builtin_amdgcn_rcpf(d01[1])};
  const f32x2 rc23={__builtin_amdgcn_rcpf(d23[0]),__builtin_amdgcn_rcpf(d23[1])};
  const f32x2 th01 = rc01*-2.0f + 1.0f;
  const f32x2 th23 = rc23*-2.0f + 1.0f;
  const f32x2 om01 = 1.0f - rc01, om23 = 1.0f - rc23;
  const f32x2 sv01 = (rc01*g4)*om01, sv23 = (rc23*g4)*om23;
  const int el0=q*4;
  hdst[(el0+0)*72+jw]=f2bf1(th01[0]);
  hdst[(el0+1)*72+jw]=f2bf1(th01[1]);
  hdst[(el0+2)*72+jw]=f2bf1(th23[0]);
  hdst[(el0+3)*72+jw]=f2bf1(th23[1]);
  sdstf[(el0+0)*76+jw]=sv01[0];
  sdstf[(el0+1)*76+jw]=sv01[1];
  sdstf[(el0+2)*76+jw]=sv23[0];
  sdstf[(el0+3)*76+jw]=sv23[1];
}

// R11: (256,3) locked (6 failed occupancy experiments: force-4/512t/no-bounds
// all give 2/1 blocks or spill; 3 blocks is the achievable optimum).
// NEW: GEMM1 operand-swap kills the vt LDS round-trip. Computing
// Dt=mfma(W1^T-tile-as-A, a0-as-B) yields V1 transposed IN REGISTERS: lane
// holds V1[i=lane&15][j=16g+4q+r] — exactly GEMM2's A-frag rows. k-order is
// permuted (pi=16g+4q+r at slot (kk,q,j)); w2tf is built with matching pi so
// the contraction is identical. MFMA count unchanged (8 = 4g x 2kk vs old
// 2np x 2acc x 2kk). Deleted per el: 16 ds_write + 2 ds_read_b128 + 2 WV +
// vt (9.2 KB LDS). w1gA (32 VGPR) replaces b1fr (32): net-zero registers.
__global__ __launch_bounds__(256,3) void traj_kernel(Params p){
  __shared__ __align__(16) float w0f[DD][76];              // W0[a][i] f32, padded
  __shared__ __align__(16) float w3tt[HH][20];             // W3[j][a] fp32 (trace)
  __shared__ __align__(16) unsigned short w0t[HH][16];     // W0^T[jw][k<16] bf16 (L0 B-frag)
  __shared__ __align__(16) unsigned short b3f[2][64][8];   // L3 B-frags (lane-only)
  __shared__ __align__(16) unsigned short w2tf[2][4][64][8]; // GEMM2 B-frags, pi-permuted k
  __shared__ __align__(16) float4 lscA[3][64];             // {g,gb,hb,b} per col, layers 0-2
  __shared__ __align__(16) float4 lsc3[16];                // layer 3 (by m)
  __shared__ __align__(16) unsigned short xh[DD][16];      // x hi-bf16 (K>=16 via zero frag)
  __shared__ __align__(16) unsigned short xl[DD][16];      // x lo-bf16
  __shared__ __align__(16) unsigned short hbh[2][EPB][72]; // bf16 activations (ping-pong)
  __shared__ __align__(16) float sb0f[EPB][76];            // s0 f32, padded
  __shared__ __align__(16) unsigned short sb12[2][EPB][72];// s1,s2 bf16
  __shared__ __align__(16) float sig3w[4][DD];
  __shared__ __align__(16) float dxs[4][4][17];            // per-wave dx slice [wv][r][m]

  const int tid = threadIdx.x;
  const int e   = tid>>4;
  const int a   = tid&15;
  const int wv  = tid>>6;
  const int lane= tid&63;
  const int m   = lane&15;
  const int q   = lane>>4;
  const int b   = blockIdx.x*EPB + e;
  const int jw  = wv*16 + m;     // forward output column of this lane

  // ---- persistent register weight fragments ----
  short8 f1fr[2], f2fr[2];
  short8 w1gA[4][2];   // A-operand of W1^T tile g: lane holds W1[k=kk*32+q*8+j][g*16+m]
  {
    #pragma unroll
    for(int kk=0;kk<2;++kk){
      #pragma unroll
      for(int j=0;j<8;++j){
        const int k=kk*32+q*8+j;
        f1fr[kk][j]=(short)f2bf(p.W1[k*HH+jw]);
        f2fr[kk][j]=(short)f2bf(p.W2[k*HH+jw]);
      }
      #pragma unroll
      for(int g=0;g<4;++g){
        #pragma unroll
        for(int j=0;j<8;++j){
          const int k=kk*32+q*8+j;
          w1gA[g][kk][j]=(short)f2bf(p.W1[k*HH + g*16 + m]);
        }
      }
    }
  }

  // ---- one-time LDS staging ----
  for(int idx=tid; idx<DD*HH; idx+=256) w0f[idx>>6][idx&63]=p.W0[idx];    // f32
  for(int idx=tid; idx<HH*DD; idx+=256) w3tt[idx>>4][idx&15]=p.W3[idx];   // fp32
  for(int idx=tid; idx<HH*16; idx+=256){
    const int c_=idx>>4, k=idx&15;
    w0t[c_][k]=f2bf(p.W0[k*HH+c_]);
  }
  for(int idx=tid; idx<1024; idx+=256){
    const int kk=idx>>9, ln=(idx>>3)&63, j=idx&7;
    const int k=kk*32+(ln>>4)*8+j;
    b3f[kk][ln][j]=f2bf(p.W3[k*DD+(ln&15)]);
  }
  for(int idx=tid; idx<4096; idx+=256){       // GEMM2 B-frags with pi k-order
    const int j=idx&7, ln=(idx>>3)&63, nt=(idx>>9)&3, kk=idx>>11;
    const int qq=(ln>>4)&3;
    const int t=kk*8+j;
    const int k=16*(t>>2) + 4*qq + (t&3);      // pi(kk,q,j) = 16g+4q+r
    w2tf[kk][nt][ln][j]=f2bf(p.W2[k*HH+4*(ln&15)+nt]);
  }
  if(tid<64)            lscA[0][tid]    =make_float4(p.g0[tid],p.gb0[tid],p.hb0[tid],p.b0[tid]);
  else if(tid<128)      lscA[1][tid-64] =make_float4(p.g1[tid-64],p.gb1[tid-64],p.hb1[tid-64],p.b1[tid-64]);
  else if(tid<192)      lscA[2][tid-128]=make_float4(p.g2[tid-128],p.gb2[tid-128],p.hb2[tid-128],p.b2[tid-128]);
  else if(tid<208)      lsc3[tid-192]   =make_float4(p.g3[tid-192],p.gb3[tid-192],p.hb3[tid-192],p.b3[tid-192]);
  __syncthreads();

  float zbx = p.x0[b*DD+a];
  p.out[b*DD+a]=zbx;
  float trp[4]={0.f,0.f,0.f,0.f};
  float dvp=0.f;

  #pragma unroll 1
  for(int step=0; step<2; ++step){
    const float t0=p.ts[step], t1=p.ts[step+1];
    const float hs=t1-t0;
    float dzx=0.f;
    float zwx=zbx;
    #pragma unroll 1
    for(int stage=0; stage<4; ++stage){
      const float cin=(stage==0)?0.f:((stage==3)?1.f:0.5f);
      const float tcur=t0+cin*hs;
      const float wg=(stage==0||stage==3)?1.f:2.f;
      const float fs=hs*(1.f/6.f)*wg;
      const float fs5=0.5f*fs;

      // producer writes x as pre-split hi/lo bf16
      {
        const unsigned ux=__float_as_uint(zwx);
        xh[e][a]=(unsigned short)(ux>>16);
        xl[e][a]=f2bf1(zwx-__uint_as_float(ux&0xFFFF0000u));
      }
      __syncthreads();                       // B1 (also: prior el-loop reads done)

      // ---------- L0: X @ W0 (hi/lo; K>=16 rows zero via zero frags) ----------
      float4 sc0=lscA[0][jw];
      f32x4 c={sc0.w,sc0.w,sc0.w,sc0.w};
      {
        short8 f0fr=short8{0,0,0,0,0,0,0,0};
        short8 ah=f0fr, al=f0fr;
        if(q<2){
          f0fr=*reinterpret_cast<const short8*>(&w0t[jw][q*8]);
          ah  =*reinterpret_cast<const short8*>(&xh[m][q*8]);
          al  =*reinterpret_cast<const short8*>(&xl[m][q*8]);
        }
        c=MFMA(ah,f0fr,c); c=MFMA(al,f0fr,c);
      }
      fwd_epi0(c,tcur,sc0,&hbh[0][0][0],&sb0f[0][0],jw,q);
      __syncthreads();                       // B2

      // ---------- L1 ----------
      float4 sc1=lscA[1][jw];
      c=f32x4{sc1.w,sc1.w,sc1.w,sc1.w};
      #pragma unroll
      for(int kk=0;kk<2;++kk){
        const short8 ah=*reinterpret_cast<const short8*>(&hbh[0][m][kk*32+q*8]);
        c=MFMA(ah,f1fr[kk],c);
      }
      fwd_epi(c,tcur,sc1,&hbh[1][0][0],&sb12[0][0][0],jw,q);
      __syncthreads();                       // B3

      // ---------- L2 ----------
      float4 sc2=lscA[2][jw];
      c=f32x4{sc2.w,sc2.w,sc2.w,sc2.w};
      #pragma unroll
      for(int kk=0;kk<2;++kk){
        const short8 ah=*reinterpret_cast<const short8*>(&hbh[1][m][kk*32+q*8]);
        c=MFMA(ah,f2fr[kk],c);
      }
      fwd_epi(c,tcur,sc2,&hbh[0][0][0],&sb12[1][0][0],jw,q);  // h2 -> buf0
      __syncthreads();                       // B4

      // ---------- L3: dx ----------
      float4 sc3=lsc3[m];
      c=f32x4{sc3.w,sc3.w,sc3.w,sc3.w};
      #pragma unroll
      for(int kk=0;kk<2;++kk){
        const short8 bf3=*reinterpret_cast<const short8*>(&b3f[kk][lane][0]);
        const short8 ah=*reinterpret_cast<const short8*>(&hbh[0][m][kk*32+q*8]);
        c=MFMA(ah,bf3,c);
      }
      const float gate3=sigm(tcur*sc3.x+sc3.y);
      const float tb3=tcur*sc3.z;
      if(q==wv){
        #pragma unroll
        for(int r=0;r<4;++r)
          dxs[wv][r][m]=c[r]*gate3+tb3;
      }
      if(q==0) sig3w[wv][m]=gate3;
      WV();
      const float dxk=dxs[wv][q][m];         // = dx[e][a]
      dvp += fs5*dxk*dxk;

      // ---------- trace factors (once per stage, pk) ----------
      f32x2 tf2[4][2];
      {
        const f32x4 sg4=*reinterpret_cast<const f32x4*>(&sig3w[wv][q*4]);
        const f32x2 sgA={sg4[0],sg4[1]}, sgB={sg4[2],sg4[3]};
        #pragma unroll
        for(int nt=0;nt<4;++nt){
          const f32x4 w4=*reinterpret_cast<const f32x4*>(&w3tt[4*m+nt][q*4]);
          tf2[nt][0]=sgA*f32x2{w4[0],w4[1]};
          tf2[nt][1]=sgB*f32x2{w4[2],w4[3]};
        }
      }

      // ---------- tangent per element: vt-free via transposed GEMM1 ----------
      #pragma unroll
      for(int el=0; el<4; ++el){
        const int ee=wv*4+el;
        // A0 = W0 (f32) ⊙ s0 (f32) -> bf16 pack; no unpacking
        Frag a0[2];
        #pragma unroll
        for(int kk=0;kk<2;++kk){
          const f32x4 wa=*reinterpret_cast<const f32x4*>(&w0f[m][kk*32+q*8]);
          const f32x4 wb=*reinterpret_cast<const f32x4*>(&w0f[m][kk*32+q*8+4]);
          const f32x4 sa=*reinterpret_cast<const f32x4*>(&sb0f[ee][kk*32+q*8]);
          const f32x4 sc_=*reinterpret_cast<const f32x4*>(&sb0f[ee][kk*32+q*8+4]);
          a0[kk].d[0]=pk2bf(wa[0]*sa[0], wa[1]*sa[1]);
          a0[kk].d[1]=pk2bf(wa[2]*sa[2], wa[3]*sa[3]);
          a0[kk].d[2]=pk2bf(wb[0]*sc_[0], wb[1]*sc_[1]);
          a0[kk].d[3]=pk2bf(wb[2]*sc_[2], wb[3]*sc_[3]);
        }
        // GEMM1 transposed: Dt[g] rows j=16g+4q+r, cols i=m (lane-local V1 row)
        f32x4 dt0={0,0,0,0}, dt1={0,0,0,0}, dt2={0,0,0,0}, dt3={0,0,0,0};
        #pragma unroll
        for(int kk=0;kk<2;++kk){
          dt0=MFMA(w1gA[0][kk], a0[kk].s, dt0);
          dt1=MFMA(w1gA[1][kk], a0[kk].s, dt1);
          dt2=MFMA(w1gA[2][kk], a0[kk].s, dt2);
          dt3=MFMA(w1gA[3][kk], a0[kk].s, dt3);
        }
        // scale by s1[j] and pack straight into GEMM2 A-frags (pi k-order)
        const unsigned* s1p=reinterpret_cast<const unsigned*>(&sb12[0][ee][0]);
        Frag a2[2];
        #pragma unroll
        for(int g=0; g<4; ++g){
          const unsigned da=s1p[8*g+2*q], db=s1p[8*g+2*q+1];
          const f32x4 s={__uint_as_float(da<<16),__uint_as_float(da&0xFFFF0000u),
                         __uint_as_float(db<<16),__uint_as_float(db&0xFFFF0000u)};
          const f32x4 v=(g==0?dt0:(g==1?dt1:(g==2?dt2:dt3)))*s;
          a2[g>>1].d[(g&1)*2+0]=pk2bf(v[0],v[1]);
          a2[g>>1].d[(g&1)*2+1]=pk2bf(v[2],v[3]);
        }
        // GEMM2 in nt pairs, B-frags streamed from LDS (pi-matched table)
        float tr=0.f;
        #pragma unroll
        for(int np=0; np<2; ++np){
          f32x4 cA={0,0,0,0}, cB={0,0,0,0};
          #pragma unroll
          for(int kk=0;kk<2;++kk){
            const short8 bA=*reinterpret_cast<const short8*>(&w2tf[kk][2*np  ][lane][0]);
            const short8 bB=*reinterpret_cast<const short8*>(&w2tf[kk][2*np+1][lane][0]);
            cA=MFMA(a2[kk].s,bA,cA);
            cB=MFMA(a2[kk].s,bB,cB);
          }
          const unsigned s2d=*reinterpret_cast<const unsigned*>(&sb12[1][ee][4*m+2*np]);
          const float s20=__uint_as_float(s2d<<16), s21=__uint_as_float(s2d&0xFFFF0000u);
          const f32x2 tA = f32x2{cA[0],cA[1]}*tf2[2*np  ][0] + f32x2{cA[2],cA[3]}*tf2[2*np  ][1];
          const f32x2 tB = f32x2{cB[0],cB[1]}*tf2[2*np+1][0] + f32x2{cB[2],cB[3]}*tf2[2*np+1][1];
          tr += (tA[0]+tA[1])*s20 + (tB[0]+tB[1])*s21;
        }
        trp[el] += fs*tr;
      }

      // ---------- RK4 state update ----------
      dzx += fs*dxk;
      const float cn=(stage==2)?1.f:0.5f;
      if(stage<3) zwx=zbx+cn*hs*dxk;
    }
    zbx += dzx;
    p.out[(step+1)*(NB*DD)+b*DD+a]=zbx;
  }

  // ---------- deferred reductions ----------
  #pragma unroll
  for(int el=0; el<4; ++el){
    float v=trp[el];
    #pragma unroll
    for(int mk=32;mk>=1;mk>>=1) v+=__shfl_xor(v,mk,64);
    if(lane==el) p.out[3*NB*DD + blockIdx.x*EPB + wv*4 + el]=v;
  }
  {
    float v=dvp;
    #pragma unroll
    for(int mk=8;mk>=1;mk>>=1) v+=__shfl_xor(v,mk,16);
    if(a==0){
      p.out[3*NB*DD+NB+b]=fabsf(v);
      p.out[3*NB*DD+2*NB+b]=0.f;
    }
  }
}

extern "C" void kernel_launch(void* const* d_in, const int* in_sizes, int n_in,
                              void* d_out, int out_size, void* d_ws, size_t ws_size,
                              hipStream_t stream){
  Params p;
  p.ts  = (const float*)d_in[0];
  p.x0  = (const float*)d_in[1];
  p.W0  = (const float*)d_in[2];  p.b0 =(const float*)d_in[3];
  p.g0  = (const float*)d_in[4];  p.gb0=(const float*)d_in[5];  p.hb0=(const float*)d_in[6];
  p.W1  = (const float*)d_in[7];  p.b1 =(const float*)d_in[8];
  p.g1  = (const float*)d_in[9];  p.gb1=(const float*)d_in[10]; p.hb1=(const float*)d_in[11];
  p.W2  = (const float*)d_in[12]; p.b2 =(const float*)d_in[13];
  p.g2  = (const float*)d_in[14]; p.gb2=(const float*)d_in[15]; p.hb2=(const float*)d_in[16];
  p.W3  = (const float*)d_in[17]; p.b3 =(const float*)d_in[18];
  p.g3  = (const float*)d_in[19]; p.gb3=(const float*)d_in[20]; p.hb3=(const float*)d_in[21];
  p.out = (float*)d_out;
  hipLaunchKernelGGL(traj_kernel, dim3(NB/EPB), dim3(256), 0, stream, p);
}

// Round 12
// 244.887 us; speedup vs baseline: 1.4428x; 1.0041x over previous
//
#include <hip/hip_runtime.h>

#define NB 32768
#define DD 16
#define HH 64
#define EPB 16

typedef __attribute__((ext_vector_type(8))) short short8;
typedef __attribute__((ext_vector_type(2))) float f32x2;
typedef __attribute__((ext_vector_type(4))) float f32x4;
typedef __attribute__((ext_vector_type(4))) unsigned uint4v;

union Frag { short8 s; uint4v u; unsigned d[4]; };

struct Params {
  const float *ts, *x0;
  const float *W0,*b0,*g0,*gb0,*hb0;
  const float *W1,*b1,*g1,*gb1,*hb1;
  const float *W2,*b2,*g2,*gb2,*hb2;
  const float *W3,*b3,*g3,*gb3,*hb3;
  float *out;
};

__device__ __forceinline__ float bfs(unsigned short u){
  return __uint_as_float(((unsigned)u)<<16);
}
__device__ __forceinline__ unsigned short f2bf(float f){   // full RNE (init only)
  unsigned u=__float_as_uint(f);
  return (unsigned short)((u + 0x7FFFu + ((u>>16)&1u))>>16);
}
__device__ __forceinline__ unsigned pk2bf(float lo, float hi){
  unsigned a=__float_as_uint(lo)+0x8000u;
  unsigned b=__float_as_uint(hi)+0x8000u;
  return __builtin_amdgcn_perm(b, a, 0x07060302u);
}
__device__ __forceinline__ unsigned short f2bf1(float f){
  return (unsigned short)((__float_as_uint(f)+0x8000u)>>16);
}
__device__ __forceinline__ float sigm(float u){
  return __builtin_amdgcn_rcpf(1.0f+__builtin_amdgcn_exp2f(-1.44269504f*u));
}
#define WV() __builtin_amdgcn_wave_barrier()
#define MFMA(A,B,C) __builtin_amdgcn_mfma_f32_16x16x32_bf16((A),(B),(C),0,0,0)

// gated-tanh epilogue; sc = {g, gb, hb, b}; h -> bf16, s -> bf16
__device__ __forceinline__ void fwd_epi(const f32x4& c, float tcur,
    const float4 sc,
    unsigned short* __restrict__ hdst, unsigned short* __restrict__ sdst,
    int jw, int q)
{
  const float gate = sigm(tcur*sc.x+sc.y);
  const float gk   = gate*2.88539008f;
  const float tbk  = (tcur*sc.z)*2.88539008f;
  const float g4   = 4.0f*gate;
  const f32x2 c01={c[0],c[1]}, c23={c[2],c[3]};
  const f32x2 pre01 = c01*gk + tbk;
  const f32x2 pre23 = c23*gk + tbk;
  const f32x2 e01={__builtin_amdgcn_exp2f(pre01[0]),__builtin_amdgcn_exp2f(pre01[1])};
  const f32x2 e23={__builtin_amdgcn_exp2f(pre23[0]),__builtin_amdgcn_exp2f(pre23[1])};
  const f32x2 d01=e01+1.0f, d23=e23+1.0f;
  const f32x2 rc01={__builtin_amdgcn_rcpf(d01[0]),__builtin_amdgcn_rcpf(d01[1])};
  const f32x2 rc23={__builtin_amdgcn_rcpf(d23[0]),__builtin_amdgcn_rcpf(d23[1])};
  const f32x2 th01 = rc01*-2.0f + 1.0f;
  const f32x2 th23 = rc23*-2.0f + 1.0f;
  const f32x2 om01 = 1.0f - rc01, om23 = 1.0f - rc23;
  const f32x2 sv01 = (rc01*g4)*om01, sv23 = (rc23*g4)*om23;
  const int el0=q*4;
  hdst[(el0+0)*72+jw]=f2bf1(th01[0]);
  hdst[(el0+1)*72+jw]=f2bf1(th01[1]);
  hdst[(el0+2)*72+jw]=f2bf1(th23[0]);
  hdst[(el0+3)*72+jw]=f2bf1(th23[1]);
  sdst[(el0+0)*72+jw]=f2bf1(sv01[0]);
  sdst[(el0+1)*72+jw]=f2bf1(sv01[1]);
  sdst[(el0+2)*72+jw]=f2bf1(sv23[0]);
  sdst[(el0+3)*72+jw]=f2bf1(sv23[1]);
}

// layer-0 variant: s written as f32 at stride 76 (padded, conflict-free)
__device__ __forceinline__ void fwd_epi0(const f32x4& c, float tcur,
    const float4 sc,
    unsigned short* __restrict__ hdst, float* __restrict__ sdstf,
    int jw, int q)
{
  const float gate = sigm(tcur*sc.x+sc.y);
  const float gk   = gate*2.88539008f;
  const float tbk  = (tcur*sc.z)*2.88539008f;
  const float g4   = 4.0f*gate;
  const f32x2 c01={c[0],c[1]}, c23={c[2],c[3]};
  const f32x2 pre01 = c01*gk + tbk;
  const f32x2 pre23 = c23*gk + tbk;
  const f32x2 e01={__builtin_amdgcn_exp2f(pre01[0]),__builtin_amdgcn_exp2f(pre01[1])};
  const f32x2 e23={__builtin_amdgcn_exp2f(pre23[0]),__builtin_amdgcn_exp2f(pre23[1])};
  const f32x2 d01=e01+1.0f, d23=e23+1.0f;
  const f32x2 rc01={__builtin_amdgcn_rcpf(d01[0]),__builtin_amdgcn_rcpf(d01[1])};
  const f32x2 rc23={__builtin_amdgcn_rcpf(d23[0]),__builtin_amdgcn_rcpf(d23[1])};
  const f32x2 th01 = rc01*-2.0f + 1.0f;
  const f32x2 th23 = rc23*-2.0f + 1.0f;
  const f32x2 om01 = 1.0f - rc01, om23 = 1.0f - rc23;
  const f32x2 sv01 = (rc01*g4)*om01, sv23 = (rc23*g4)*om23;
  const int el0=q*4;
  hdst[(el0+0)*72+jw]=f2bf1(th01[0]);
  hdst[(el0+1)*72+jw]=f2bf1(th01[1]);
  hdst[(el0+2)*72+jw]=f2bf1(th23[0]);
  hdst[(el0+3)*72+jw]=f2bf1(th23[1]);
  sdstf[(el0+0)*76+jw]=sv01[0];
  sdstf[(el0+1)*76+jw]=sv01[1];
  sdstf[(el0+2)*76+jw]=sv23[0];
  sdstf[(el0+3)*76+jw]=sv23[1];
}

// R12: R11's vt-free transposed-GEMM1 structure, ANTI-SPILL version. R11
// spilled (FETCH 1.3->10.5MB, WRITE->52.6MB) because 4 dt accumulators were
// simultaneously live (+16 VGPR peak > 84 clamp). Now g-tiles processed in
// PAIRS: dt pair (8 regs) -> scale -> pack into a2[gp] -> accumulators reused.
// Peak transient ~20 vs 32. Conflicts stay at R11's 4.2M (vt round-trip gone);
// MFMA count and numerics identical to R11 (passed).
__global__ __launch_bounds__(256,3) void traj_kernel(Params p){
  __shared__ __align__(16) float w0f[DD][76];              // W0[a][i] f32, padded
  __shared__ __align__(16) float w3tt[HH][20];             // W3[j][a] fp32 (trace)
  __shared__ __align__(16) unsigned short w0t[HH][16];     // W0^T[jw][k<16] bf16 (L0 B-frag)
  __shared__ __align__(16) unsigned short b3f[2][64][8];   // L3 B-frags (lane-only)
  __shared__ __align__(16) unsigned short w2tf[2][4][64][8]; // GEMM2 B-frags, pi-permuted k
  __shared__ __align__(16) float4 lscA[3][64];             // {g,gb,hb,b} per col, layers 0-2
  __shared__ __align__(16) float4 lsc3[16];                // layer 3 (by m)
  __shared__ __align__(16) unsigned short xh[DD][16];      // x hi-bf16 (K>=16 via zero frag)
  __shared__ __align__(16) unsigned short xl[DD][16];      // x lo-bf16
  __shared__ __align__(16) unsigned short hbh[2][EPB][72]; // bf16 activations (ping-pong)
  __shared__ __align__(16) float sb0f[EPB][76];            // s0 f32, padded
  __shared__ __align__(16) unsigned short sb12[2][EPB][72];// s1,s2 bf16
  __shared__ __align__(16) float sig3w[4][DD];
  __shared__ __align__(16) float dxs[4][4][17];            // per-wave dx slice [wv][r][m]

  const int tid = threadIdx.x;
  const int e   = tid>>4;
  const int a   = tid&15;
  const int wv  = tid>>6;
  const int lane= tid&63;
  const int m   = lane&15;
  const int q   = lane>>4;
  const int b   = blockIdx.x*EPB + e;
  const int jw  = wv*16 + m;     // forward output column of this lane

  // ---- persistent register weight fragments ----
  short8 f1fr[2], f2fr[2];
  short8 w1gA[4][2];   // A-operand of W1^T tile g: lane holds W1[k=kk*32+q*8+j][g*16+m]
  {
    #pragma unroll
    for(int kk=0;kk<2;++kk){
      #pragma unroll
      for(int j=0;j<8;++j){
        const int k=kk*32+q*8+j;
        f1fr[kk][j]=(short)f2bf(p.W1[k*HH+jw]);
        f2fr[kk][j]=(short)f2bf(p.W2[k*HH+jw]);
      }
      #pragma unroll
      for(int g=0;g<4;++g){
        #pragma unroll
        for(int j=0;j<8;++j){
          const int k=kk*32+q*8+j;
          w1gA[g][kk][j]=(short)f2bf(p.W1[k*HH + g*16 + m]);
        }
      }
    }
  }

  // ---- one-time LDS staging ----
  for(int idx=tid; idx<DD*HH; idx+=256) w0f[idx>>6][idx&63]=p.W0[idx];    // f32
  for(int idx=tid; idx<HH*DD; idx+=256) w3tt[idx>>4][idx&15]=p.W3[idx];   // fp32
  for(int idx=tid; idx<HH*16; idx+=256){
    const int c_=idx>>4, k=idx&15;
    w0t[c_][k]=f2bf(p.W0[k*HH+c_]);
  }
  for(int idx=tid; idx<1024; idx+=256){
    const int kk=idx>>9, ln=(idx>>3)&63, j=idx&7;
    const int k=kk*32+(ln>>4)*8+j;
    b3f[kk][ln][j]=f2bf(p.W3[k*DD+(ln&15)]);
  }
  for(int idx=tid; idx<4096; idx+=256){       // GEMM2 B-frags with pi k-order
    const int j=idx&7, ln=(idx>>3)&63, nt=(idx>>9)&3, kk=idx>>11;
    const int qq=(ln>>4)&3;
    const int t=kk*8+j;
    const int k=16*(t>>2) + 4*qq + (t&3);      // pi(kk,q,j) = 16g+4q+r
    w2tf[kk][nt][ln][j]=f2bf(p.W2[k*HH+4*(ln&15)+nt]);
  }
  if(tid<64)            lscA[0][tid]    =make_float4(p.g0[tid],p.gb0[tid],p.hb0[tid],p.b0[tid]);
  else if(tid<128)      lscA[1][tid-64] =make_float4(p.g1[tid-64],p.gb1[tid-64],p.hb1[tid-64],p.b1[tid-64]);
  else if(tid<192)      lscA[2][tid-128]=make_float4(p.g2[tid-128],p.gb2[tid-128],p.hb2[tid-128],p.b2[tid-128]);
  else if(tid<208)      lsc3[tid-192]   =make_float4(p.g3[tid-192],p.gb3[tid-192],p.hb3[tid-192],p.b3[tid-192]);
  __syncthreads();

  float zbx = p.x0[b*DD+a];
  p.out[b*DD+a]=zbx;
  float trp[4]={0.f,0.f,0.f,0.f};
  float dvp=0.f;

  #pragma unroll 1
  for(int step=0; step<2; ++step){
    const float t0=p.ts[step], t1=p.ts[step+1];
    const float hs=t1-t0;
    float dzx=0.f;
    float zwx=zbx;
    #pragma unroll 1
    for(int stage=0; stage<4; ++stage){
      const float cin=(stage==0)?0.f:((stage==3)?1.f:0.5f);
      const float tcur=t0+cin*hs;
      const float wg=(stage==0||stage==3)?1.f:2.f;
      const float fs=hs*(1.f/6.f)*wg;
      const float fs5=0.5f*fs;

      // producer writes x as pre-split hi/lo bf16
      {
        const unsigned ux=__float_as_uint(zwx);
        xh[e][a]=(unsigned short)(ux>>16);
        xl[e][a]=f2bf1(zwx-__uint_as_float(ux&0xFFFF0000u));
      }
      __syncthreads();                       // B1

      // ---------- L0: X @ W0 (hi/lo; K>=16 rows zero via zero frags) ----------
      float4 sc0=lscA[0][jw];
      f32x4 c={sc0.w,sc0.w,sc0.w,sc0.w};
      {
        short8 f0fr=short8{0,0,0,0,0,0,0,0};
        short8 ah=f0fr, al=f0fr;
        if(q<2){
          f0fr=*reinterpret_cast<const short8*>(&w0t[jw][q*8]);
          ah  =*reinterpret_cast<const short8*>(&xh[m][q*8]);
          al  =*reinterpret_cast<const short8*>(&xl[m][q*8]);
        }
        c=MFMA(ah,f0fr,c); c=MFMA(al,f0fr,c);
      }
      fwd_epi0(c,tcur,sc0,&hbh[0][0][0],&sb0f[0][0],jw,q);
      __syncthreads();                       // B2

      // ---------- L1 ----------
      float4 sc1=lscA[1][jw];
      c=f32x4{sc1.w,sc1.w,sc1.w,sc1.w};
      #pragma unroll
      for(int kk=0;kk<2;++kk){
        const short8 ah=*reinterpret_cast<const short8*>(&hbh[0][m][kk*32+q*8]);
        c=MFMA(ah,f1fr[kk],c);
      }
      fwd_epi(c,tcur,sc1,&hbh[1][0][0],&sb12[0][0][0],jw,q);
      __syncthreads();                       // B3

      // ---------- L2 ----------
      float4 sc2=lscA[2][jw];
      c=f32x4{sc2.w,sc2.w,sc2.w,sc2.w};
      #pragma unroll
      for(int kk=0;kk<2;++kk){
        const short8 ah=*reinterpret_cast<const short8*>(&hbh[1][m][kk*32+q*8]);
        c=MFMA(ah,f2fr[kk],c);
      }
      fwd_epi(c,tcur,sc2,&hbh[0][0][0],&sb12[1][0][0],jw,q);  // h2 -> buf0
      __syncthreads();                       // B4

      // ---------- L3: dx ----------
      float4 sc3=lsc3[m];
      c=f32x4{sc3.w,sc3.w,sc3.w,sc3.w};
      #pragma unroll
      for(int kk=0;kk<2;++kk){
        const short8 bf3=*reinterpret_cast<const short8*>(&b3f[kk][lane][0]);
        const short8 ah=*reinterpret_cast<const short8*>(&hbh[0][m][kk*32+q*8]);
        c=MFMA(ah,bf3,c);
      }
      const float gate3=sigm(tcur*sc3.x+sc3.y);
      const float tb3=tcur*sc3.z;
      if(q==wv){
        #pragma unroll
        for(int r=0;r<4;++r)
          dxs[wv][r][m]=c[r]*gate3+tb3;
      }
      if(q==0) sig3w[wv][m]=gate3;
      WV();
      const float dxk=dxs[wv][q][m];         // = dx[e][a]
      dvp += fs5*dxk*dxk;

      // ---------- trace factors (once per stage, pk) ----------
      f32x2 tf2[4][2];
      {
        const f32x4 sg4=*reinterpret_cast<const f32x4*>(&sig3w[wv][q*4]);
        const f32x2 sgA={sg4[0],sg4[1]}, sgB={sg4[2],sg4[3]};
        #pragma unroll
        for(int nt=0;nt<4;++nt){
          const f32x4 w4=*reinterpret_cast<const f32x4*>(&w3tt[4*m+nt][q*4]);
          tf2[nt][0]=sgA*f32x2{w4[0],w4[1]};
          tf2[nt][1]=sgB*f32x2{w4[2],w4[3]};
        }
      }

      // ---------- tangent per element: vt-free, g-PAIRED accumulators ----------
      #pragma unroll
      for(int el=0; el<4; ++el){
        const int ee=wv*4+el;
        // A0 = W0 (f32) ⊙ s0 (f32) -> bf16 pack; no unpacking
        Frag a0[2];
        #pragma unroll
        for(int kk=0;kk<2;++kk){
          const f32x4 wa=*reinterpret_cast<const f32x4*>(&w0f[m][kk*32+q*8]);
          const f32x4 wb=*reinterpret_cast<const f32x4*>(&w0f[m][kk*32+q*8+4]);
          const f32x4 sa=*reinterpret_cast<const f32x4*>(&sb0f[ee][kk*32+q*8]);
          const f32x4 sc_=*reinterpret_cast<const f32x4*>(&sb0f[ee][kk*32+q*8+4]);
          a0[kk].d[0]=pk2bf(wa[0]*sa[0], wa[1]*sa[1]);
          a0[kk].d[1]=pk2bf(wa[2]*sa[2], wa[3]*sa[3]);
          a0[kk].d[2]=pk2bf(wb[0]*sc_[0], wb[1]*sc_[1]);
          a0[kk].d[3]=pk2bf(wb[2]*sc_[2], wb[3]*sc_[3]);
        }
        // GEMM1 transposed in g-PAIRS (only 2 acc quads live at once)
        const unsigned* s1p=reinterpret_cast<const unsigned*>(&sb12[0][ee][0]);
        Frag a2[2];
        #pragma unroll
        for(int gp=0; gp<2; ++gp){
          f32x4 dtA={0,0,0,0}, dtB={0,0,0,0};
          #pragma unroll
          for(int kk=0;kk<2;++kk){
            dtA=MFMA(w1gA[2*gp  ][kk], a0[kk].s, dtA);
            dtB=MFMA(w1gA[2*gp+1][kk], a0[kk].s, dtB);
          }
          {
            const unsigned da=s1p[8*(2*gp)+2*q], db=s1p[8*(2*gp)+2*q+1];
            const f32x4 s={__uint_as_float(da<<16),__uint_as_float(da&0xFFFF0000u),
                           __uint_as_float(db<<16),__uint_as_float(db&0xFFFF0000u)};
            const f32x4 v=dtA*s;
            a2[gp].d[0]=pk2bf(v[0],v[1]);
            a2[gp].d[1]=pk2bf(v[2],v[3]);
          }
          {
            const unsigned da=s1p[8*(2*gp+1)+2*q], db=s1p[8*(2*gp+1)+2*q+1];
            const f32x4 s={__uint_as_float(da<<16),__uint_as_float(da&0xFFFF0000u),
                           __uint_as_float(db<<16),__uint_as_float(db&0xFFFF0000u)};
            const f32x4 v=dtB*s;
            a2[gp].d[2]=pk2bf(v[0],v[1]);
            a2[gp].d[3]=pk2bf(v[2],v[3]);
          }
        }
        // GEMM2 in nt pairs, B-frags streamed from LDS (pi-matched table)
        float tr=0.f;
        #pragma unroll
        for(int np=0; np<2; ++np){
          f32x4 cA={0,0,0,0}, cB={0,0,0,0};
          #pragma unroll
          for(int kk=0;kk<2;++kk){
            const short8 bA=*reinterpret_cast<const short8*>(&w2tf[kk][2*np  ][lane][0]);
            const short8 bB=*reinterpret_cast<const short8*>(&w2tf[kk][2*np+1][lane][0]);
            cA=MFMA(a2[kk].s,bA,cA);
            cB=MFMA(a2[kk].s,bB,cB);
          }
          const unsigned s2d=*reinterpret_cast<const unsigned*>(&sb12[1][ee][4*m+2*np]);
          const float s20=__uint_as_float(s2d<<16), s21=__uint_as_float(s2d&0xFFFF0000u);
          const f32x2 tA = f32x2{cA[0],cA[1]}*tf2[2*np  ][0] + f32x2{cA[2],cA[3]}*tf2[2*np  ][1];
          const f32x2 tB = f32x2{cB[0],cB[1]}*tf2[2*np+1][0] + f32x2{cB[2],cB[3]}*tf2[2*np+1][1];
          tr += (tA[0]+tA[1])*s20 + (tB[0]+tB[1])*s21;
        }
        trp[el] += fs*tr;
      }

      // ---------- RK4 state update ----------
      dzx += fs*dxk;
      const float cn=(stage==2)?1.f:0.5f;
      if(stage<3) zwx=zbx+cn*hs*dxk;
    }
    zbx += dzx;
    p.out[(step+1)*(NB*DD)+b*DD+a]=zbx;
  }

  // ---------- deferred reductions ----------
  #pragma unroll
  for(int el=0; el<4; ++el){
    float v=trp[el];
    #pragma unroll
    for(int mk=32;mk>=1;mk>>=1) v+=__shfl_xor(v,mk,64);
    if(lane==el) p.out[3*NB*DD + blockIdx.x*EPB + wv*4 + el]=v;
  }
  {
    float v=dvp;
    #pragma unroll
    for(int mk=8;mk>=1;mk>>=1) v+=__shfl_xor(v,mk,16);
    if(a==0){
      p.out[3*NB*DD+NB+b]=fabsf(v);
      p.out[3*NB*DD+2*NB+b]=0.f;
    }
  }
}

extern "C" void kernel_launch(void* const* d_in, const int* in_sizes, int n_in,
                              void* d_out, int out_size, void* d_ws, size_t ws_size,
                              hipStream_t stream){
  Params p;
  p.ts  = (const float*)d_in[0];
  p.x0  = (const float*)d_in[1];
  p.W0  = (const float*)d_in[2];  p.b0 =(const float*)d_in[3];
  p.g0  = (const float*)d_in[4];  p.gb0=(const float*)d_in[5];  p.hb0=(const float*)d_in[6];
  p.W1  = (const float*)d_in[7];  p.b1 =(const float*)d_in[8];
  p.g1  = (const float*)d_in[9];  p.gb1=(const float*)d_in[10]; p.hb1=(const float*)d_in[11];
  p.W2  = (const float*)d_in[12]; p.b2 =(const float*)d_in[13];
  p.g2  = (const float*)d_in[14]; p.gb2=(const float*)d_in[15]; p.hb2=(const float*)d_in[16];
  p.W3  = (const float*)d_in[17]; p.b3 =(const float*)d_in[18];
  p.g3  = (const float*)d_in[19]; p.gb3=(const float*)d_in[20]; p.hb3=(const float*)d_in[21];
  p.out = (float*)d_out;
  hipLaunchKernelGGL(traj_kernel, dim3(NB/EPB), dim3(256), 0, stream, p);
}

// Round 13
// 224.105 us; speedup vs baseline: 1.5766x; 1.0927x over previous
//
#include <hip/hip_runtime.h>

#define NB 32768
#define DD 16
#define HH 64
#define EPB 16

typedef __attribute__((ext_vector_type(8))) short short8;
typedef __attribute__((ext_vector_type(2))) float f32x2;
typedef __attribute__((ext_vector_type(4))) float f32x4;
typedef __attribute__((ext_vector_type(4))) unsigned uint4v;

union Frag { short8 s; uint4v u; unsigned d[4]; };

struct Params {
  const float *ts, *x0;
  const float *W0,*b0,*g0,*gb0,*hb0;
  const float *W1,*b1,*g1,*gb1,*hb1;
  const float *W2,*b2,*g2,*gb2,*hb2;
  const float *W3,*b3,*g3,*gb3,*hb3;
  float *out;
};

__device__ __forceinline__ float bfs(unsigned short u){
  return __uint_as_float(((unsigned)u)<<16);
}
__device__ __forceinline__ unsigned short f2bf(float f){   // full RNE (init only)
  unsigned u=__float_as_uint(f);
  return (unsigned short)((u + 0x7FFFu + ((u>>16)&1u))>>16);
}
__device__ __forceinline__ unsigned pk2bf(float lo, float hi){
  unsigned a=__float_as_uint(lo)+0x8000u;
  unsigned b=__float_as_uint(hi)+0x8000u;
  return __builtin_amdgcn_perm(b, a, 0x07060302u);
}
__device__ __forceinline__ unsigned short f2bf1(float f){
  return (unsigned short)((__float_as_uint(f)+0x8000u)>>16);
}
__device__ __forceinline__ float sigm(float u){
  return __builtin_amdgcn_rcpf(1.0f+__builtin_amdgcn_exp2f(-1.44269504f*u));
}
#define WV() __builtin_amdgcn_wave_barrier()
#define SB0() __builtin_amdgcn_sched_barrier(0)
#define MFMA(A,B,C) __builtin_amdgcn_mfma_f32_16x16x32_bf16((A),(B),(C),0,0,0)

// gated-tanh epilogue; sc = {g, gb, hb, b}; h -> bf16, s -> bf16
__device__ __forceinline__ void fwd_epi(const f32x4& c, float tcur,
    const float4 sc,
    unsigned short* __restrict__ hdst, unsigned short* __restrict__ sdst,
    int jw, int q)
{
  const float gate = sigm(tcur*sc.x+sc.y);
  const float gk   = gate*2.88539008f;
  const float tbk  = (tcur*sc.z)*2.88539008f;
  const float g4   = 4.0f*gate;
  const f32x2 c01={c[0],c[1]}, c23={c[2],c[3]};
  const f32x2 pre01 = c01*gk + tbk;
  const f32x2 pre23 = c23*gk + tbk;
  const f32x2 e01={__builtin_amdgcn_exp2f(pre01[0]),__builtin_amdgcn_exp2f(pre01[1])};
  const f32x2 e23={__builtin_amdgcn_exp2f(pre23[0]),__builtin_amdgcn_exp2f(pre23[1])};
  const f32x2 d01=e01+1.0f, d23=e23+1.0f;
  const f32x2 rc01={__builtin_amdgcn_rcpf(d01[0]),__builtin_amdgcn_rcpf(d01[1])};
  const f32x2 rc23={__builtin_amdgcn_rcpf(d23[0]),__builtin_amdgcn_rcpf(d23[1])};
  const f32x2 th01 = rc01*-2.0f + 1.0f;
  const f32x2 th23 = rc23*-2.0f + 1.0f;
  const f32x2 om01 = 1.0f - rc01, om23 = 1.0f - rc23;
  const f32x2 sv01 = (rc01*g4)*om01, sv23 = (rc23*g4)*om23;
  const int el0=q*4;
  hdst[(el0+0)*72+jw]=f2bf1(th01[0]);
  hdst[(el0+1)*72+jw]=f2bf1(th01[1]);
  hdst[(el0+2)*72+jw]=f2bf1(th23[0]);
  hdst[(el0+3)*72+jw]=f2bf1(th23[1]);
  sdst[(el0+0)*72+jw]=f2bf1(sv01[0]);
  sdst[(el0+1)*72+jw]=f2bf1(sv01[1]);
  sdst[(el0+2)*72+jw]=f2bf1(sv23[0]);
  sdst[(el0+3)*72+jw]=f2bf1(sv23[1]);
}

// layer-0 variant: s written as f32 at stride 76 (padded, conflict-free)
__device__ __forceinline__ void fwd_epi0(const f32x4& c, float tcur,
    const float4 sc,
    unsigned short* __restrict__ hdst, float* __restrict__ sdstf,
    int jw, int q)
{
  const float gate = sigm(tcur*sc.x+sc.y);
  const float gk   = gate*2.88539008f;
  const float tbk  = (tcur*sc.z)*2.88539008f;
  const float g4   = 4.0f*gate;
  const f32x2 c01={c[0],c[1]}, c23={c[2],c[3]};
  const f32x2 pre01 = c01*gk + tbk;
  const f32x2 pre23 = c23*gk + tbk;
  const f32x2 e01={__builtin_amdgcn_exp2f(pre01[0]),__builtin_amdgcn_exp2f(pre01[1])};
  const f32x2 e23={__builtin_amdgcn_exp2f(pre23[0]),__builtin_amdgcn_exp2f(pre23[1])};
  const f32x2 d01=e01+1.0f, d23=e23+1.0f;
  const f32x2 rc01={__builtin_amdgcn_rcpf(d01[0]),__builtin_amdgcn_rcpf(d01[1])};
  const f32x2 rc23={__builtin_amdgcn_rcpf(d23[0]),__builtin_amdgcn_rcpf(d23[1])};
  const f32x2 th01 = rc01*-2.0f + 1.0f;
  const f32x2 th23 = rc23*-2.0f + 1.0f;
  const f32x2 om01 = 1.0f - rc01, om23 = 1.0f - rc23;
  const f32x2 sv01 = (rc01*g4)*om01, sv23 = (rc23*g4)*om23;
  const int el0=q*4;
  hdst[(el0+0)*72+jw]=f2bf1(th01[0]);
  hdst[(el0+1)*72+jw]=f2bf1(th01[1]);
  hdst[(el0+2)*72+jw]=f2bf1(th23[0]);
  hdst[(el0+3)*72+jw]=f2bf1(th23[1]);
  sdstf[(el0+0)*76+jw]=sv01[0];
  sdstf[(el0+1)*76+jw]=sv01[1];
  sdstf[(el0+2)*76+jw]=sv23[0];
  sdstf[(el0+3)*76+jw]=sv23[1];
}

// R13: R12 + sched_barrier(0) fences at el-iteration boundaries. R11/R12
// spilled NOT from within-el pressure (~24 transient, same as R7) but from
// the scheduler interleaving all 4 unrolled els (hoisted a0 builds etc.)
// past the 84-reg clamp — R7 was implicitly fenced by its LDS write->WV->read
// chain; the vt-free el-loop has no such fence. SB0 pins cross-el motion,
// capping peak pressure at single-el scope while leaving intra-el scheduling
// free (3-wave TLP covers the latency). Everything else identical to R12.
__global__ __launch_bounds__(256,3) void traj_kernel(Params p){
  __shared__ __align__(16) float w0f[DD][76];              // W0[a][i] f32, padded
  __shared__ __align__(16) float w3tt[HH][20];             // W3[j][a] fp32 (trace)
  __shared__ __align__(16) unsigned short w0t[HH][16];     // W0^T[jw][k<16] bf16 (L0 B-frag)
  __shared__ __align__(16) unsigned short b3f[2][64][8];   // L3 B-frags (lane-only)
  __shared__ __align__(16) unsigned short w2tf[2][4][64][8]; // GEMM2 B-frags, pi-permuted k
  __shared__ __align__(16) float4 lscA[3][64];             // {g,gb,hb,b} per col, layers 0-2
  __shared__ __align__(16) float4 lsc3[16];                // layer 3 (by m)
  __shared__ __align__(16) unsigned short xh[DD][16];      // x hi-bf16 (K>=16 via zero frag)
  __shared__ __align__(16) unsigned short xl[DD][16];      // x lo-bf16
  __shared__ __align__(16) unsigned short hbh[2][EPB][72]; // bf16 activations (ping-pong)
  __shared__ __align__(16) float sb0f[EPB][76];            // s0 f32, padded
  __shared__ __align__(16) unsigned short sb12[2][EPB][72];// s1,s2 bf16
  __shared__ __align__(16) float sig3w[4][DD];
  __shared__ __align__(16) float dxs[4][4][17];            // per-wave dx slice [wv][r][m]

  const int tid = threadIdx.x;
  const int e   = tid>>4;
  const int a   = tid&15;
  const int wv  = tid>>6;
  const int lane= tid&63;
  const int m   = lane&15;
  const int q   = lane>>4;
  const int b   = blockIdx.x*EPB + e;
  const int jw  = wv*16 + m;     // forward output column of this lane

  // ---- persistent register weight fragments ----
  short8 f1fr[2], f2fr[2];
  short8 w1gA[4][2];   // A-operand of W1^T tile g: lane holds W1[k=kk*32+q*8+j][g*16+m]
  {
    #pragma unroll
    for(int kk=0;kk<2;++kk){
      #pragma unroll
      for(int j=0;j<8;++j){
        const int k=kk*32+q*8+j;
        f1fr[kk][j]=(short)f2bf(p.W1[k*HH+jw]);
        f2fr[kk][j]=(short)f2bf(p.W2[k*HH+jw]);
      }
      #pragma unroll
      for(int g=0;g<4;++g){
        #pragma unroll
        for(int j=0;j<8;++j){
          const int k=kk*32+q*8+j;
          w1gA[g][kk][j]=(short)f2bf(p.W1[k*HH + g*16 + m]);
        }
      }
    }
  }

  // ---- one-time LDS staging ----
  for(int idx=tid; idx<DD*HH; idx+=256) w0f[idx>>6][idx&63]=p.W0[idx];    // f32
  for(int idx=tid; idx<HH*DD; idx+=256) w3tt[idx>>4][idx&15]=p.W3[idx];   // fp32
  for(int idx=tid; idx<HH*16; idx+=256){
    const int c_=idx>>4, k=idx&15;
    w0t[c_][k]=f2bf(p.W0[k*HH+c_]);
  }
  for(int idx=tid; idx<1024; idx+=256){
    const int kk=idx>>9, ln=(idx>>3)&63, j=idx&7;
    const int k=kk*32+(ln>>4)*8+j;
    b3f[kk][ln][j]=f2bf(p.W3[k*DD+(ln&15)]);
  }
  for(int idx=tid; idx<4096; idx+=256){       // GEMM2 B-frags with pi k-order
    const int j=idx&7, ln=(idx>>3)&63, nt=(idx>>9)&3, kk=idx>>11;
    const int qq=(ln>>4)&3;
    const int t=kk*8+j;
    const int k=16*(t>>2) + 4*qq + (t&3);      // pi(kk,q,j) = 16g+4q+r
    w2tf[kk][nt][ln][j]=f2bf(p.W2[k*HH+4*(ln&15)+nt]);
  }
  if(tid<64)            lscA[0][tid]    =make_float4(p.g0[tid],p.gb0[tid],p.hb0[tid],p.b0[tid]);
  else if(tid<128)      lscA[1][tid-64] =make_float4(p.g1[tid-64],p.gb1[tid-64],p.hb1[tid-64],p.b1[tid-64]);
  else if(tid<192)      lscA[2][tid-128]=make_float4(p.g2[tid-128],p.gb2[tid-128],p.hb2[tid-128],p.b2[tid-128]);
  else if(tid<208)      lsc3[tid-192]   =make_float4(p.g3[tid-192],p.gb3[tid-192],p.hb3[tid-192],p.b3[tid-192]);
  __syncthreads();

  float zbx = p.x0[b*DD+a];
  p.out[b*DD+a]=zbx;
  float trp[4]={0.f,0.f,0.f,0.f};
  float dvp=0.f;

  #pragma unroll 1
  for(int step=0; step<2; ++step){
    const float t0=p.ts[step], t1=p.ts[step+1];
    const float hs=t1-t0;
    float dzx=0.f;
    float zwx=zbx;
    #pragma unroll 1
    for(int stage=0; stage<4; ++stage){
      const float cin=(stage==0)?0.f:((stage==3)?1.f:0.5f);
      const float tcur=t0+cin*hs;
      const float wg=(stage==0||stage==3)?1.f:2.f;
      const float fs=hs*(1.f/6.f)*wg;
      const float fs5=0.5f*fs;

      // producer writes x as pre-split hi/lo bf16
      {
        const unsigned ux=__float_as_uint(zwx);
        xh[e][a]=(unsigned short)(ux>>16);
        xl[e][a]=f2bf1(zwx-__uint_as_float(ux&0xFFFF0000u));
      }
      __syncthreads();                       // B1

      // ---------- L0: X @ W0 (hi/lo; K>=16 rows zero via zero frags) ----------
      float4 sc0=lscA[0][jw];
      f32x4 c={sc0.w,sc0.w,sc0.w,sc0.w};
      {
        short8 f0fr=short8{0,0,0,0,0,0,0,0};
        short8 ah=f0fr, al=f0fr;
        if(q<2){
          f0fr=*reinterpret_cast<const short8*>(&w0t[jw][q*8]);
          ah  =*reinterpret_cast<const short8*>(&xh[m][q*8]);
          al  =*reinterpret_cast<const short8*>(&xl[m][q*8]);
        }
        c=MFMA(ah,f0fr,c); c=MFMA(al,f0fr,c);
      }
      fwd_epi0(c,tcur,sc0,&hbh[0][0][0],&sb0f[0][0],jw,q);
      __syncthreads();                       // B2

      // ---------- L1 ----------
      float4 sc1=lscA[1][jw];
      c=f32x4{sc1.w,sc1.w,sc1.w,sc1.w};
      #pragma unroll
      for(int kk=0;kk<2;++kk){
        const short8 ah=*reinterpret_cast<const short8*>(&hbh[0][m][kk*32+q*8]);
        c=MFMA(ah,f1fr[kk],c);
      }
      fwd_epi(c,tcur,sc1,&hbh[1][0][0],&sb12[0][0][0],jw,q);
      __syncthreads();                       // B3

      // ---------- L2 ----------
      float4 sc2=lscA[2][jw];
      c=f32x4{sc2.w,sc2.w,sc2.w,sc2.w};
      #pragma unroll
      for(int kk=0;kk<2;++kk){
        const short8 ah=*reinterpret_cast<const short8*>(&hbh[1][m][kk*32+q*8]);
        c=MFMA(ah,f2fr[kk],c);
      }
      fwd_epi(c,tcur,sc2,&hbh[0][0][0],&sb12[1][0][0],jw,q);  // h2 -> buf0
      __syncthreads();                       // B4

      // ---------- L3: dx ----------
      float4 sc3=lsc3[m];
      c=f32x4{sc3.w,sc3.w,sc3.w,sc3.w};
      #pragma unroll
      for(int kk=0;kk<2;++kk){
        const short8 bf3=*reinterpret_cast<const short8*>(&b3f[kk][lane][0]);
        const short8 ah=*reinterpret_cast<const short8*>(&hbh[0][m][kk*32+q*8]);
        c=MFMA(ah,bf3,c);
      }
      const float gate3=sigm(tcur*sc3.x+sc3.y);
      const float tb3=tcur*sc3.z;
      if(q==wv){
        #pragma unroll
        for(int r=0;r<4;++r)
          dxs[wv][r][m]=c[r]*gate3+tb3;
      }
      if(q==0) sig3w[wv][m]=gate3;
      WV();
      const float dxk=dxs[wv][q][m];         // = dx[e][a]
      dvp += fs5*dxk*dxk;

      // ---------- trace factors (once per stage, pk) ----------
      f32x2 tf2[4][2];
      {
        const f32x4 sg4=*reinterpret_cast<const f32x4*>(&sig3w[wv][q*4]);
        const f32x2 sgA={sg4[0],sg4[1]}, sgB={sg4[2],sg4[3]};
        #pragma unroll
        for(int nt=0;nt<4;++nt){
          const f32x4 w4=*reinterpret_cast<const f32x4*>(&w3tt[4*m+nt][q*4]);
          tf2[nt][0]=sgA*f32x2{w4[0],w4[1]};
          tf2[nt][1]=sgB*f32x2{w4[2],w4[3]};
        }
      }

      // ---------- tangent per element: vt-free, g-paired, el-fenced ----------
      #pragma unroll
      for(int el=0; el<4; ++el){
        const int ee=wv*4+el;
        // A0 = W0 (f32) ⊙ s0 (f32) -> bf16 pack; no unpacking
        Frag a0[2];
        #pragma unroll
        for(int kk=0;kk<2;++kk){
          const f32x4 wa=*reinterpret_cast<const f32x4*>(&w0f[m][kk*32+q*8]);
          const f32x4 wb=*reinterpret_cast<const f32x4*>(&w0f[m][kk*32+q*8+4]);
          const f32x4 sa=*reinterpret_cast<const f32x4*>(&sb0f[ee][kk*32+q*8]);
          const f32x4 sc_=*reinterpret_cast<const f32x4*>(&sb0f[ee][kk*32+q*8+4]);
          a0[kk].d[0]=pk2bf(wa[0]*sa[0], wa[1]*sa[1]);
          a0[kk].d[1]=pk2bf(wa[2]*sa[2], wa[3]*sa[3]);
          a0[kk].d[2]=pk2bf(wb[0]*sc_[0], wb[1]*sc_[1]);
          a0[kk].d[3]=pk2bf(wb[2]*sc_[2], wb[3]*sc_[3]);
        }
        // GEMM1 transposed in g-PAIRS (only 2 acc quads live at once)
        const unsigned* s1p=reinterpret_cast<const unsigned*>(&sb12[0][ee][0]);
        Frag a2[2];
        #pragma unroll
        for(int gp=0; gp<2; ++gp){
          f32x4 dtA={0,0,0,0}, dtB={0,0,0,0};
          #pragma unroll
          for(int kk=0;kk<2;++kk){
            dtA=MFMA(w1gA[2*gp  ][kk], a0[kk].s, dtA);
            dtB=MFMA(w1gA[2*gp+1][kk], a0[kk].s, dtB);
          }
          {
            const unsigned da=s1p[8*(2*gp)+2*q], db=s1p[8*(2*gp)+2*q+1];
            const f32x4 s={__uint_as_float(da<<16),__uint_as_float(da&0xFFFF0000u),
                           __uint_as_float(db<<16),__uint_as_float(db&0xFFFF0000u)};
            const f32x4 v=dtA*s;
            a2[gp].d[0]=pk2bf(v[0],v[1]);
            a2[gp].d[1]=pk2bf(v[2],v[3]);
          }
          {
            const unsigned da=s1p[8*(2*gp+1)+2*q], db=s1p[8*(2*gp+1)+2*q+1];
            const f32x4 s={__uint_as_float(da<<16),__uint_as_float(da&0xFFFF0000u),
                           __uint_as_float(db<<16),__uint_as_float(db&0xFFFF0000u)};
            const f32x4 v=dtB*s;
            a2[gp].d[2]=pk2bf(v[0],v[1]);
            a2[gp].d[3]=pk2bf(v[2],v[3]);
          }
        }
        // GEMM2 in nt pairs, B-frags streamed from LDS (pi-matched table)
        float tr=0.f;
        #pragma unroll
        for(int np=0; np<2; ++np){
          f32x4 cA={0,0,0,0}, cB={0,0,0,0};
          #pragma unroll
          for(int kk=0;kk<2;++kk){
            const short8 bA=*reinterpret_cast<const short8*>(&w2tf[kk][2*np  ][lane][0]);
            const short8 bB=*reinterpret_cast<const short8*>(&w2tf[kk][2*np+1][lane][0]);
            cA=MFMA(a2[kk].s,bA,cA);
            cB=MFMA(a2[kk].s,bB,cB);
          }
          const unsigned s2d=*reinterpret_cast<const unsigned*>(&sb12[1][ee][4*m+2*np]);
          const float s20=__uint_as_float(s2d<<16), s21=__uint_as_float(s2d&0xFFFF0000u);
          const f32x2 tA = f32x2{cA[0],cA[1]}*tf2[2*np  ][0] + f32x2{cA[2],cA[3]}*tf2[2*np  ][1];
          const f32x2 tB = f32x2{cB[0],cB[1]}*tf2[2*np+1][0] + f32x2{cB[2],cB[3]}*tf2[2*np+1][1];
          tr += (tA[0]+tA[1])*s20 + (tB[0]+tB[1])*s21;
        }
        trp[el] += fs*tr;
        SB0();                               // fence: no cross-el code motion
      }

      // ---------- RK4 state update ----------
      dzx += fs*dxk;
      const float cn=(stage==2)?1.f:0.5f;
      if(stage<3) zwx=zbx+cn*hs*dxk;
    }
    zbx += dzx;
    p.out[(step+1)*(NB*DD)+b*DD+a]=zbx;
  }

  // ---------- deferred reductions ----------
  #pragma unroll
  for(int el=0; el<4; ++el){
    float v=trp[el];
    #pragma unroll
    for(int mk=32;mk>=1;mk>>=1) v+=__shfl_xor(v,mk,64);
    if(lane==el) p.out[3*NB*DD + blockIdx.x*EPB + wv*4 + el]=v;
  }
  {
    float v=dvp;
    #pragma unroll
    for(int mk=8;mk>=1;mk>>=1) v+=__shfl_xor(v,mk,16);
    if(a==0){
      p.out[3*NB*DD+NB+b]=fabsf(v);
      p.out[3*NB*DD+2*NB+b]=0.f;
    }
  }
}

extern "C" void kernel_launch(void* const* d_in, const int* in_sizes, int n_in,
                              void* d_out, int out_size, void* d_ws, size_t ws_size,
                              hipStream_t stream){
  Params p;
  p.ts  = (const float*)d_in[0];
  p.x0  = (const float*)d_in[1];
  p.W0  = (const float*)d_in[2];  p.b0 =(const float*)d_in[3];
  p.g0  = (const float*)d_in[4];  p.gb0=(const float*)d_in[5];  p.hb0=(const float*)d_in[6];
  p.W1  = (const float*)d_in[7];  p.b1 =(const float*)d_in[8];
  p.g1  = (const float*)d_in[9];  p.gb1=(const float*)d_in[10]; p.hb1=(const float*)d_in[11];
  p.W2  = (const float*)d_in[12]; p.b2 =(const float*)d_in[13];
  p.g2  = (const float*)d_in[14]; p.gb2=(const float*)d_in[15]; p.hb2=(const float*)d_in[16];
  p.W3  = (const float*)d_in[17]; p.b3 =(const float*)d_in[18];
  p.g3  = (const float*)d_in[19]; p.gb3=(const float*)d_in[20]; p.hb3=(const float*)d_in[21];
  p.out = (float*)d_out;
  hipLaunchKernelGGL(traj_kernel, dim3(NB/EPB), dim3(256), 0, stream, p);
}

// Round 14
// 221.730 us; speedup vs baseline: 1.5935x; 1.0107x over previous
//
#include <hip/hip_runtime.h>

#define NB 32768
#define DD 16
#define HH 64
#define EPB 16

typedef __attribute__((ext_vector_type(8))) short short8;
typedef __attribute__((ext_vector_type(2))) float f32x2;
typedef __attribute__((ext_vector_type(4))) float f32x4;
typedef __attribute__((ext_vector_type(4))) unsigned uint4v;

union Frag { short8 s; uint4v u; unsigned d[4]; };

struct Params {
  const float *ts, *x0;
  const float *W0,*b0,*g0,*gb0,*hb0;
  const float *W1,*b1,*g1,*gb1,*hb1;
  const float *W2,*b2,*g2,*gb2,*hb2;
  const float *W3,*b3,*g3,*gb3,*hb3;
  float *out;
};

__device__ __forceinline__ float bfs(unsigned short u){
  return __uint_as_float(((unsigned)u)<<16);
}
__device__ __forceinline__ unsigned short f2bf(float f){   // full RNE (init only)
  unsigned u=__float_as_uint(f);
  return (unsigned short)((u + 0x7FFFu + ((u>>16)&1u))>>16);
}
__device__ __forceinline__ unsigned pk2bf(float lo, float hi){
  unsigned a=__float_as_uint(lo)+0x8000u;
  unsigned b=__float_as_uint(hi)+0x8000u;
  return __builtin_amdgcn_perm(b, a, 0x07060302u);
}
__device__ __forceinline__ unsigned short f2bf1(float f){
  return (unsigned short)((__float_as_uint(f)+0x8000u)>>16);
}
__device__ __forceinline__ float sigm(float u){
  return __builtin_amdgcn_rcpf(1.0f+__builtin_amdgcn_exp2f(-1.44269504f*u));
}
#define WV() __builtin_amdgcn_wave_barrier()
#define SB0() __builtin_amdgcn_sched_barrier(0)
#define MFMA(A,B,C) __builtin_amdgcn_mfma_f32_16x16x32_bf16((A),(B),(C),0,0,0)

// unified epilogue: h -> bf16 (stride 72), s -> f32 (stride 76, conflict-free)
__device__ __forceinline__ void fwd_epi0(const f32x4& c, float tcur,
    const float4 sc,
    unsigned short* __restrict__ hdst, float* __restrict__ sdstf,
    int jw, int q)
{
  const float gate = sigm(tcur*sc.x+sc.y);
  const float gk   = gate*2.88539008f;
  const float tbk  = (tcur*sc.z)*2.88539008f;
  const float g4   = 4.0f*gate;
  const f32x2 c01={c[0],c[1]}, c23={c[2],c[3]};
  const f32x2 pre01 = c01*gk + tbk;
  const f32x2 pre23 = c23*gk + tbk;
  const f32x2 e01={__builtin_amdgcn_exp2f(pre01[0]),__builtin_amdgcn_exp2f(pre01[1])};
  const f32x2 e23={__builtin_amdgcn_exp2f(pre23[0]),__builtin_amdgcn_exp2f(pre23[1])};
  const f32x2 d01=e01+1.0f, d23=e23+1.0f;
  const f32x2 rc01={__builtin_amdgcn_rcpf(d01[0]),__builtin_amdgcn_rcpf(d01[1])};
  const f32x2 rc23={__builtin_amdgcn_rcpf(d23[0]),__builtin_amdgcn_rcpf(d23[1])};
  const f32x2 th01 = rc01*-2.0f + 1.0f;
  const f32x2 th23 = rc23*-2.0f + 1.0f;
  const f32x2 om01 = 1.0f - rc01, om23 = 1.0f - rc23;
  const f32x2 sv01 = (rc01*g4)*om01, sv23 = (rc23*g4)*om23;
  const int el0=q*4;
  hdst[(el0+0)*72+jw]=f2bf1(th01[0]);
  hdst[(el0+1)*72+jw]=f2bf1(th01[1]);
  hdst[(el0+2)*72+jw]=f2bf1(th23[0]);
  hdst[(el0+3)*72+jw]=f2bf1(th23[1]);
  sdstf[(el0+0)*76+jw]=sv01[0];
  sdstf[(el0+1)*76+jw]=sv01[1];
  sdstf[(el0+2)*76+jw]=sv23[0];
  sdstf[(el0+3)*76+jw]=sv23[1];
}

// R14: R13 (vt-free + SB0 fences, 157.4us) + s1/s2 stored f32 (extends R7's
// s0->f32 win). Kills per-el s1/s2 dword unpacking (~140 VALU/stage): s1 scale
// is now one aligned f32x4 per dt-quad (same-address across q-groups ->
// broadcast, conflict-free), s2 one f32x2; L1/L2 epilogues drop 8 f2bf1 packs.
// LDS ~47.6K <= 53248 -> still 3 blocks/CU. Numerics move toward f32 ref.
__global__ __launch_bounds__(256,3) void traj_kernel(Params p){
  __shared__ __align__(16) float w0f[DD][76];              // W0[a][i] f32, padded
  __shared__ __align__(16) float w3tt[HH][20];             // W3[j][a] fp32 (trace)
  __shared__ __align__(16) unsigned short w0t[HH][16];     // W0^T[jw][k<16] bf16 (L0 B-frag)
  __shared__ __align__(16) unsigned short b3f[2][64][8];   // L3 B-frags (lane-only)
  __shared__ __align__(16) unsigned short w2tf[2][4][64][8]; // GEMM2 B-frags, pi-permuted k
  __shared__ __align__(16) float4 lscA[3][64];             // {g,gb,hb,b} per col, layers 0-2
  __shared__ __align__(16) float4 lsc3[16];                // layer 3 (by m)
  __shared__ __align__(16) unsigned short xh[DD][16];      // x hi-bf16 (K>=16 via zero frag)
  __shared__ __align__(16) unsigned short xl[DD][16];      // x lo-bf16
  __shared__ __align__(16) unsigned short hbh[2][EPB][72]; // bf16 activations (ping-pong)
  __shared__ __align__(16) float sb0f[EPB][76];            // s0 f32, padded
  __shared__ __align__(16) float sb1f[EPB][76];            // s1 f32, padded
  __shared__ __align__(16) float sb2f[EPB][76];            // s2 f32, padded
  __shared__ __align__(16) float sig3w[4][DD];
  __shared__ __align__(16) float dxs[4][4][17];            // per-wave dx slice [wv][r][m]

  const int tid = threadIdx.x;
  const int e   = tid>>4;
  const int a   = tid&15;
  const int wv  = tid>>6;
  const int lane= tid&63;
  const int m   = lane&15;
  const int q   = lane>>4;
  const int b   = blockIdx.x*EPB + e;
  const int jw  = wv*16 + m;     // forward output column of this lane

  // ---- persistent register weight fragments ----
  short8 f1fr[2], f2fr[2];
  short8 w1gA[4][2];   // A-operand of W1^T tile g: lane holds W1[k=kk*32+q*8+j][g*16+m]
  {
    #pragma unroll
    for(int kk=0;kk<2;++kk){
      #pragma unroll
      for(int j=0;j<8;++j){
        const int k=kk*32+q*8+j;
        f1fr[kk][j]=(short)f2bf(p.W1[k*HH+jw]);
        f2fr[kk][j]=(short)f2bf(p.W2[k*HH+jw]);
      }
      #pragma unroll
      for(int g=0;g<4;++g){
        #pragma unroll
        for(int j=0;j<8;++j){
          const int k=kk*32+q*8+j;
          w1gA[g][kk][j]=(short)f2bf(p.W1[k*HH + g*16 + m]);
        }
      }
    }
  }

  // ---- one-time LDS staging ----
  for(int idx=tid; idx<DD*HH; idx+=256) w0f[idx>>6][idx&63]=p.W0[idx];    // f32
  for(int idx=tid; idx<HH*DD; idx+=256) w3tt[idx>>4][idx&15]=p.W3[idx];   // fp32
  for(int idx=tid; idx<HH*16; idx+=256){
    const int c_=idx>>4, k=idx&15;
    w0t[c_][k]=f2bf(p.W0[k*HH+c_]);
  }
  for(int idx=tid; idx<1024; idx+=256){
    const int kk=idx>>9, ln=(idx>>3)&63, j=idx&7;
    const int k=kk*32+(ln>>4)*8+j;
    b3f[kk][ln][j]=f2bf(p.W3[k*DD+(ln&15)]);
  }
  for(int idx=tid; idx<4096; idx+=256){       // GEMM2 B-frags with pi k-order
    const int j=idx&7, ln=(idx>>3)&63, nt=(idx>>9)&3, kk=idx>>11;
    const int qq=(ln>>4)&3;
    const int t=kk*8+j;
    const int k=16*(t>>2) + 4*qq + (t&3);      // pi(kk,q,j) = 16g+4q+r
    w2tf[kk][nt][ln][j]=f2bf(p.W2[k*HH+4*(ln&15)+nt]);
  }
  if(tid<64)            lscA[0][tid]    =make_float4(p.g0[tid],p.gb0[tid],p.hb0[tid],p.b0[tid]);
  else if(tid<128)      lscA[1][tid-64] =make_float4(p.g1[tid-64],p.gb1[tid-64],p.hb1[tid-64],p.b1[tid-64]);
  else if(tid<192)      lscA[2][tid-128]=make_float4(p.g2[tid-128],p.gb2[tid-128],p.hb2[tid-128],p.b2[tid-128]);
  else if(tid<208)      lsc3[tid-192]   =make_float4(p.g3[tid-192],p.gb3[tid-192],p.hb3[tid-192],p.b3[tid-192]);
  __syncthreads();

  float zbx = p.x0[b*DD+a];
  p.out[b*DD+a]=zbx;
  float trp[4]={0.f,0.f,0.f,0.f};
  float dvp=0.f;

  #pragma unroll 1
  for(int step=0; step<2; ++step){
    const float t0=p.ts[step], t1=p.ts[step+1];
    const float hs=t1-t0;
    float dzx=0.f;
    float zwx=zbx;
    #pragma unroll 1
    for(int stage=0; stage<4; ++stage){
      const float cin=(stage==0)?0.f:((stage==3)?1.f:0.5f);
      const float tcur=t0+cin*hs;
      const float wg=(stage==0||stage==3)?1.f:2.f;
      const float fs=hs*(1.f/6.f)*wg;
      const float fs5=0.5f*fs;

      // producer writes x as pre-split hi/lo bf16
      {
        const unsigned ux=__float_as_uint(zwx);
        xh[e][a]=(unsigned short)(ux>>16);
        xl[e][a]=f2bf1(zwx-__uint_as_float(ux&0xFFFF0000u));
      }
      __syncthreads();                       // B1

      // ---------- L0: X @ W0 (hi/lo; K>=16 rows zero via zero frags) ----------
      float4 sc0=lscA[0][jw];
      f32x4 c={sc0.w,sc0.w,sc0.w,sc0.w};
      {
        short8 f0fr=short8{0,0,0,0,0,0,0,0};
        short8 ah=f0fr, al=f0fr;
        if(q<2){
          f0fr=*reinterpret_cast<const short8*>(&w0t[jw][q*8]);
          ah  =*reinterpret_cast<const short8*>(&xh[m][q*8]);
          al  =*reinterpret_cast<const short8*>(&xl[m][q*8]);
        }
        c=MFMA(ah,f0fr,c); c=MFMA(al,f0fr,c);
      }
      fwd_epi0(c,tcur,sc0,&hbh[0][0][0],&sb0f[0][0],jw,q);
      __syncthreads();                       // B2

      // ---------- L1 ----------
      float4 sc1=lscA[1][jw];
      c=f32x4{sc1.w,sc1.w,sc1.w,sc1.w};
      #pragma unroll
      for(int kk=0;kk<2;++kk){
        const short8 ah=*reinterpret_cast<const short8*>(&hbh[0][m][kk*32+q*8]);
        c=MFMA(ah,f1fr[kk],c);
      }
      fwd_epi0(c,tcur,sc1,&hbh[1][0][0],&sb1f[0][0],jw,q);
      __syncthreads();                       // B3

      // ---------- L2 ----------
      float4 sc2=lscA[2][jw];
      c=f32x4{sc2.w,sc2.w,sc2.w,sc2.w};
      #pragma unroll
      for(int kk=0;kk<2;++kk){
        const short8 ah=*reinterpret_cast<const short8*>(&hbh[1][m][kk*32+q*8]);
        c=MFMA(ah,f2fr[kk],c);
      }
      fwd_epi0(c,tcur,sc2,&hbh[0][0][0],&sb2f[0][0],jw,q);  // h2 -> buf0
      __syncthreads();                       // B4

      // ---------- L3: dx ----------
      float4 sc3=lsc3[m];
      c=f32x4{sc3.w,sc3.w,sc3.w,sc3.w};
      #pragma unroll
      for(int kk=0;kk<2;++kk){
        const short8 bf3=*reinterpret_cast<const short8*>(&b3f[kk][lane][0]);
        const short8 ah=*reinterpret_cast<const short8*>(&hbh[0][m][kk*32+q*8]);
        c=MFMA(ah,bf3,c);
      }
      const float gate3=sigm(tcur*sc3.x+sc3.y);
      const float tb3=tcur*sc3.z;
      if(q==wv){
        #pragma unroll
        for(int r=0;r<4;++r)
          dxs[wv][r][m]=c[r]*gate3+tb3;
      }
      if(q==0) sig3w[wv][m]=gate3;
      WV();
      const float dxk=dxs[wv][q][m];         // = dx[e][a]
      dvp += fs5*dxk*dxk;

      // ---------- trace factors (once per stage, pk) ----------
      f32x2 tf2[4][2];
      {
        const f32x4 sg4=*reinterpret_cast<const f32x4*>(&sig3w[wv][q*4]);
        const f32x2 sgA={sg4[0],sg4[1]}, sgB={sg4[2],sg4[3]};
        #pragma unroll
        for(int nt=0;nt<4;++nt){
          const f32x4 w4=*reinterpret_cast<const f32x4*>(&w3tt[4*m+nt][q*4]);
          tf2[nt][0]=sgA*f32x2{w4[0],w4[1]};
          tf2[nt][1]=sgB*f32x2{w4[2],w4[3]};
        }
      }

      // ---------- tangent per element: vt-free, g-paired, el-fenced ----------
      #pragma unroll
      for(int el=0; el<4; ++el){
        const int ee=wv*4+el;
        // A0 = W0 (f32) ⊙ s0 (f32) -> bf16 pack; no unpacking
        Frag a0[2];
        #pragma unroll
        for(int kk=0;kk<2;++kk){
          const f32x4 wa=*reinterpret_cast<const f32x4*>(&w0f[m][kk*32+q*8]);
          const f32x4 wb=*reinterpret_cast<const f32x4*>(&w0f[m][kk*32+q*8+4]);
          const f32x4 sa=*reinterpret_cast<const f32x4*>(&sb0f[ee][kk*32+q*8]);
          const f32x4 sc_=*reinterpret_cast<const f32x4*>(&sb0f[ee][kk*32+q*8+4]);
          a0[kk].d[0]=pk2bf(wa[0]*sa[0], wa[1]*sa[1]);
          a0[kk].d[1]=pk2bf(wa[2]*sa[2], wa[3]*sa[3]);
          a0[kk].d[2]=pk2bf(wb[0]*sc_[0], wb[1]*sc_[1]);
          a0[kk].d[3]=pk2bf(wb[2]*sc_[2], wb[3]*sc_[3]);
        }
        // GEMM1 transposed in g-PAIRS; s1 as aligned f32x4 (broadcast reads)
        Frag a2[2];
        #pragma unroll
        for(int gp=0; gp<2; ++gp){
          f32x4 dtA={0,0,0,0}, dtB={0,0,0,0};
          #pragma unroll
          for(int kk=0;kk<2;++kk){
            dtA=MFMA(w1gA[2*gp  ][kk], a0[kk].s, dtA);
            dtB=MFMA(w1gA[2*gp+1][kk], a0[kk].s, dtB);
          }
          {
            const f32x4 s=*reinterpret_cast<const f32x4*>(&sb1f[ee][(2*gp)*16+4*q]);
            const f32x4 v=dtA*s;
            a2[gp].d[0]=pk2bf(v[0],v[1]);
            a2[gp].d[1]=pk2bf(v[2],v[3]);
          }
          {
            const f32x4 s=*reinterpret_cast<const f32x4*>(&sb1f[ee][(2*gp+1)*16+4*q]);
            const f32x4 v=dtB*s;
            a2[gp].d[2]=pk2bf(v[0],v[1]);
            a2[gp].d[3]=pk2bf(v[2],v[3]);
          }
        }
        // GEMM2 in nt pairs, B-frags streamed from LDS (pi-matched table)
        float tr=0.f;
        #pragma unroll
        for(int np=0; np<2; ++np){
          f32x4 cA={0,0,0,0}, cB={0,0,0,0};
          #pragma unroll
          for(int kk=0;kk<2;++kk){
            const short8 bA=*reinterpret_cast<const short8*>(&w2tf[kk][2*np  ][lane][0]);
            const short8 bB=*reinterpret_cast<const short8*>(&w2tf[kk][2*np+1][lane][0]);
            cA=MFMA(a2[kk].s,bA,cA);
            cB=MFMA(a2[kk].s,bB,cB);
          }
          const f32x2 s2v=*reinterpret_cast<const f32x2*>(&sb2f[ee][4*m+2*np]);
          const f32x2 tA = f32x2{cA[0],cA[1]}*tf2[2*np  ][0] + f32x2{cA[2],cA[3]}*tf2[2*np  ][1];
          const f32x2 tB = f32x2{cB[0],cB[1]}*tf2[2*np+1][0] + f32x2{cB[2],cB[3]}*tf2[2*np+1][1];
          tr += (tA[0]+tA[1])*s2v[0] + (tB[0]+tB[1])*s2v[1];
        }
        trp[el] += fs*tr;
        SB0();                               // fence: no cross-el code motion
      }

      // ---------- RK4 state update ----------
      dzx += fs*dxk;
      const float cn=(stage==2)?1.f:0.5f;
      if(stage<3) zwx=zbx+cn*hs*dxk;
    }
    zbx += dzx;
    p.out[(step+1)*(NB*DD)+b*DD+a]=zbx;
  }

  // ---------- deferred reductions ----------
  #pragma unroll
  for(int el=0; el<4; ++el){
    float v=trp[el];
    #pragma unroll
    for(int mk=32;mk>=1;mk>>=1) v+=__shfl_xor(v,mk,64);
    if(lane==el) p.out[3*NB*DD + blockIdx.x*EPB + wv*4 + el]=v;
  }
  {
    float v=dvp;
    #pragma unroll
    for(int mk=8;mk>=1;mk>>=1) v+=__shfl_xor(v,mk,16);
    if(a==0){
      p.out[3*NB*DD+NB+b]=fabsf(v);
      p.out[3*NB*DD+2*NB+b]=0.f;
    }
  }
}

extern "C" void kernel_launch(void* const* d_in, const int* in_sizes, int n_in,
                              void* d_out, int out_size, void* d_ws, size_t ws_size,
                              hipStream_t stream){
  Params p;
  p.ts  = (const float*)d_in[0];
  p.x0  = (const float*)d_in[1];
  p.W0  = (const float*)d_in[2];  p.b0 =(const float*)d_in[3];
  p.g0  = (const float*)d_in[4];  p.gb0=(const float*)d_in[5];  p.hb0=(const float*)d_in[6];
  p.W1  = (const float*)d_in[7];  p.b1 =(const float*)d_in[8];
  p.g1  = (const float*)d_in[9];  p.gb1=(const float*)d_in[10]; p.hb1=(const float*)d_in[11];
  p.W2  = (const float*)d_in[12]; p.b2 =(const float*)d_in[13];
  p.g2  = (const float*)d_in[14]; p.gb2=(const float*)d_in[15]; p.hb2=(const float*)d_in[16];
  p.W3  = (const float*)d_in[17]; p.b3 =(const float*)d_in[18];
  p.g3  = (const float*)d_in[19]; p.gb3=(const float*)d_in[20]; p.hb3=(const float*)d_in[21];
  p.out = (float*)d_out;
  hipLaunchKernelGGL(traj_kernel, dim3(NB/EPB), dim3(256), 0, stream, p);
}